// Round 1
// baseline (3000.766 us; speedup 1.0000x reference)
//
#include <hip/hip_runtime.h>
#include <cstdint>
#include <math.h>

#define NPTS 8192
#define NB 4
#define NG 2048
#define NK 32
#define CIN 96
#define COUT 192

typedef unsigned long long ull;

// ---------------- setup: SoA transpose + |p|^2 (bit-exact vs ref dst2) ----------------
__global__ __launch_bounds__(256) void setup_kernel(const float* __restrict__ xyz,
                                                    float* __restrict__ xs, float* __restrict__ ys,
                                                    float* __restrict__ zs, float* __restrict__ d2){
  int i = blockIdx.x*256 + threadIdx.x;
  if (i >= NB*NPTS) return;
  float x = xyz[3*i+0], y = xyz[3*i+1], z = xyz[3*i+2];
  xs[i]=x; ys[i]=y; zs[i]=z;
  d2[i] = __fadd_rn(__fadd_rn(__fmul_rn(x,x),__fmul_rn(y,y)),__fmul_rn(z,z));
}

// Fused lexicographic (hi,lo) u64 max reduce step on the VALU pipe via DPP.
// hi = float bits of a non-negative distance (order-isomorphic to u32), lo = tie-break key.
template<int CTRL>
__device__ __forceinline__ void dppmax_pair(unsigned& hi, unsigned& lo){
  unsigned ohi = (unsigned)__builtin_amdgcn_update_dpp((int)hi, (int)hi, CTRL, 0xf, 0xf, false);
  unsigned olo = (unsigned)__builtin_amdgcn_update_dpp((int)lo, (int)lo, CTRL, 0xf, 0xf, false);
  bool gt = (ohi > hi) || (ohi == hi && olo > lo);
  hi = gt ? ohi : hi;
  lo = gt ? olo : lo;
}

// ---------------- FPS: 1024 threads, Morton-sorted points, per-wave bbox pruning -------
// 16 waves x 512-point Morton chunks (8 pts/lane -> px/py/pz/D/lowb = 40 VGPRs,
// register-resident; asm-pinned so the compiler cannot remat from LDS). Per round:
// conservative bbox skip test; active path = 8-pt update + ONE fused lex-(d,lowb)
// u64 DPP chain to lane63. ONE barrier/round; all waves reduce the 16 keys;
// coords via ctab broadcast read.
__global__ __launch_bounds__(1024,4) void fps_kernel(const float* __restrict__ xyz, int* __restrict__ fps_idx){
#pragma clang fp contract(off)   // selection-critical: no fma contraction anywhere here
  extern __shared__ char smem[];
  float4* ctab = (float4*)smem;                          // 8192*16 = 131072 B
  ull*    keys = (ull*)(smem + 131072);                  // [2][16] = 256 B
  int*    hist = (int*)(smem + 131072 + 256);            // 512 cells = 2048 B
  float*  bbs  = (float*)(smem + 131072 + 256 + 2048);   // 16 waves * 6 = 384 B
  const int b = blockIdx.x, t = threadIdx.x;
  const int w = t>>6, lane = t&63;
  const float* base = xyz + (size_t)b*NPTS*3;

  // ---- init phase: load originals, global bbox, Morton cells, sort into ctab ----
  float ox[8], oy[8], oz[8];
#pragma unroll
  for (int j=0;j<8;++j){
    int p = t + 1024*j;
    ox[j]=base[3*p+0]; oy[j]=base[3*p+1]; oz[j]=base[3*p+2];
  }
  float mnx=ox[0],mxx=ox[0],mny=oy[0],mxy=oy[0],mnz=oz[0],mxz=oz[0];
#pragma unroll
  for (int j=1;j<8;++j){
    mnx=fminf(mnx,ox[j]); mxx=fmaxf(mxx,ox[j]);
    mny=fminf(mny,oy[j]); mxy=fmaxf(mxy,oy[j]);
    mnz=fminf(mnz,oz[j]); mxz=fmaxf(mxz,oz[j]);
  }
#pragma unroll
  for (int off=32; off>0; off>>=1){
    mnx=fminf(mnx,__shfl_xor(mnx,off)); mxx=fmaxf(mxx,__shfl_xor(mxx,off));
    mny=fminf(mny,__shfl_xor(mny,off)); mxy=fmaxf(mxy,__shfl_xor(mxy,off));
    mnz=fminf(mnz,__shfl_xor(mnz,off)); mxz=fmaxf(mxz,__shfl_xor(mxz,off));
  }
  if (t < 512) hist[t] = 0;
  if (lane==0){
    bbs[w*6+0]=mnx; bbs[w*6+1]=mxx; bbs[w*6+2]=mny;
    bbs[w*6+3]=mxy; bbs[w*6+4]=mnz; bbs[w*6+5]=mxz;
  }
  if (t==0) fps_idx[b*NG] = 0;
  __syncthreads();
  float gx0=1e30f,gx1=-1e30f,gy0=1e30f,gy1=-1e30f,gz0=1e30f,gz1=-1e30f;
  for (int q=0;q<16;++q){
    gx0=fminf(gx0,bbs[q*6+0]); gx1=fmaxf(gx1,bbs[q*6+1]);
    gy0=fminf(gy0,bbs[q*6+2]); gy1=fmaxf(gy1,bbs[q*6+3]);
    gz0=fminf(gz0,bbs[q*6+4]); gz1=fmaxf(gz1,bbs[q*6+5]);
  }
  const float sxv = 8.0f/fmaxf(gx1-gx0,1e-20f);
  const float syv = 8.0f/fmaxf(gy1-gy0,1e-20f);
  const float szv = 8.0f/fmaxf(gz1-gz0,1e-20f);
  int cell[8];
#pragma unroll
  for (int j=0;j<8;++j){
    int cx = min(7,(int)((ox[j]-gx0)*sxv));
    int cy = min(7,(int)((oy[j]-gy0)*syv));
    int cz = min(7,(int)((oz[j]-gz0)*szv));
    int m = (cx&1) | ((cy&1)<<1) | ((cz&1)<<2)
          | ((cx&2)<<2) | ((cy&2)<<3) | ((cz&2)<<4)
          | ((cx&4)<<4) | ((cy&4)<<5) | ((cz&4)<<6);
    cell[j]=m;
    atomicAdd(&hist[m],1);
  }
  __syncthreads();
  if (t < 64){    // wave-0 parallel exclusive prefix over 512 cells (8/lane)
    int s0[8];
#pragma unroll
    for (int j=0;j<8;++j) s0[j]=hist[t*8+j];
    int tot=0;
#pragma unroll
    for (int j=0;j<8;++j){ int v=s0[j]; s0[j]=tot; tot+=v; }
    int inc=tot;
#pragma unroll
    for (int off=1; off<64; off<<=1){
      int o=__shfl_up(inc,off);
      if (t>=off) inc+=o;
    }
    int excl=inc-tot;
#pragma unroll
    for (int j=0;j<8;++j) hist[t*8+j]=excl+s0[j];
  }
  __syncthreads();
#pragma unroll
  for (int j=0;j<8;++j){
    int pos = atomicAdd(&hist[cell[j]],1);
    ctab[pos] = make_float4(ox[j],oy[j],oz[j], __int_as_float(t+1024*j));
  }
  __syncthreads();
  // reload sorted: wave w owns positions w*512 + j*64 + lane (contiguous 512-pt chunk)
  float px[8],py[8],pz[8],D[8]; unsigned lowb[8];
  float bx0,bx1,by0,by1,bz0,bz1;
#pragma unroll
  for (int j=0;j<8;++j){
    int pos = (w<<9) + (j<<6) + lane;
    float4 c4 = ctab[pos];
    px[j]=c4.x; py[j]=c4.y; pz[j]=c4.z;
    unsigned orig = (unsigned)__float_as_int(c4.w);
    lowb[j] = ((8191u-orig)<<13) | (unsigned)pos;   // max lowb == (max dist, lowest orig)
    D[j] = 1e10f;                                   // ref init
    // pin into VGPRs: forbid LDS-rematerialization inside the round loop
    asm volatile("" : "+v"(px[j]), "+v"(py[j]), "+v"(pz[j]), "+v"(lowb[j]));
    if (j==0){ bx0=px[j]; bx1=px[j]; by0=py[j]; by1=py[j]; bz0=pz[j]; bz1=pz[j]; }
    else {
      bx0=fminf(bx0,px[j]); bx1=fmaxf(bx1,px[j]);
      by0=fminf(by0,py[j]); by1=fmaxf(by1,py[j]);
      bz0=fminf(bz0,pz[j]); bz1=fmaxf(bz1,pz[j]);
    }
  }
#pragma unroll
  for (int off=32; off>0; off>>=1){
    bx0=fminf(bx0,__shfl_xor(bx0,off)); bx1=fmaxf(bx1,__shfl_xor(bx1,off));
    by0=fminf(by0,__shfl_xor(by0,off)); by1=fmaxf(by1,__shfl_xor(by1,off));
    bz0=fminf(bz0,__shfl_xor(bz0,off)); bz1=fmaxf(bz1,__shfl_xor(bz1,off));
  }

  // ---- serial rounds ----
  float lx=base[0], ly=base[1], lz=base[2];   // seed = point 0
  float Mw = 1e10f;                           // wave's current max D
  unsigned mylow = 0;                         // wave's cached key low32
  for (int it=0; it<NG-1; ++it){
    // exact-safe skip test: LB lower-bounds dist2(center, any owned point);
    // margin 1e-4 rel >> 3e-7 max fp error -> skip only when provably no D changes
    float qx=fminf(fmaxf(lx,bx0),bx1);
    float qy=fminf(fmaxf(ly,by0),by1);
    float qz=fminf(fmaxf(lz,bz0),bz1);
    float ddx=qx-lx, ddy=qy-ly, ddz=qz-lz;
    float LB = (ddx*ddx+ddy*ddy)+ddz*ddz;
    ull* kslot = &keys[(it&1)*16 + w];
    if (LB <= Mw*1.0001f){
      float bd=-1.0f;
#pragma unroll
      for (int j=0;j<8;++j){
        float dx=px[j]-lx, dy=py[j]-ly, dz=pz[j]-lz;
        float d=(dx*dx+dy*dy)+dz*dz;
        float nd=fminf(D[j],d);
        D[j]=nd;
        bd=fmaxf(bd,nd);
      }
      unsigned bl=0;
#pragma unroll
      for (int j=0;j<8;++j){
        unsigned c2 = (lowb[j]>bl)?lowb[j]:bl;
        bl = (D[j]==bd) ? c2 : bl;
      }
      // fused lexicographic (dist-bits, lowb) wave max -> lane 63
      unsigned hi = __float_as_uint(bd), lo = bl;
      dppmax_pair<0x111>(hi,lo); dppmax_pair<0x112>(hi,lo); dppmax_pair<0x114>(hi,lo);
      dppmax_pair<0x118>(hi,lo); dppmax_pair<0x142>(hi,lo); dppmax_pair<0x143>(hi,lo);
      unsigned hw  = (unsigned)__builtin_amdgcn_readlane((int)hi,63);
      unsigned lwv = (unsigned)__builtin_amdgcn_readlane((int)lo,63);
      if (lane==63) *kslot = (((ull)hw)<<32) | (ull)lwv;
      Mw = __uint_as_float(hw);
      mylow = lwv;
    } else {
      if (lane==63) *kslot = (((ull)__float_as_uint(Mw))<<32) | (ull)mylow;
    }
    __syncthreads();                              // ONE barrier per round
    const ull* kk = keys + (it&1)*16;
    ull k = kk[0];
#pragma unroll
    for (int q=1;q<16;++q){ ull o=kk[q]; if (o>k) k=o; }
    unsigned lw = (unsigned)k;
    float4 c4 = ctab[lw & 0x1FFFu];               // broadcast ds_read_b128
    lx=c4.x; ly=c4.y; lz=c4.z;
    if (t==0) fps_idx[b*NG + it + 1] = (int)(8191u - ((lw>>13)&0x1FFFu));
  }
}

// ---------------- kNN: wave-wide exact top-32 (lexicographic (d,idx)) ----------------
__device__ __forceinline__ bool lexlt(float ad, int ai, float bd, int bi){
  return (ad < bd) || ((ad == bd) && (ai < bi));
}
__device__ __forceinline__ void sort_desc(float& d, int& i, int lane){
#pragma unroll
  for (int k=2;k<=64;k<<=1){
#pragma unroll
    for (int j=k>>1;j>0;j>>=1){
      float od = __shfl_xor(d, j);
      int   oi = __shfl_xor(i, j);
      bool dirUp = (lane & k) != 0;      // flipped -> overall descending
      bool lower = (lane & j) == 0;
      bool less  = lexlt(d,i,od,oi);
      bool keep  = (less == (lower == dirUp));
      if (!keep){ d=od; i=oi; }
    }
  }
}
__device__ __forceinline__ void merge_asc(float& d, int& i, int lane){
#pragma unroll
  for (int j=32;j>0;j>>=1){
    float od = __shfl_xor(d, j);
    int   oi = __shfl_xor(i, j);
    bool lower = (lane & j) == 0;
    bool less  = lexlt(d,i,od,oi);
    bool keep  = (less == lower);
    if (!keep){ d=od; i=oi; }
  }
}

__global__ __launch_bounds__(256) void knn_kernel(const float* __restrict__ xs, const float* __restrict__ ys,
                                                  const float* __restrict__ zs, const float* __restrict__ d2,
                                                  const int* __restrict__ fps_idx, int* __restrict__ knn_out){
  __shared__ float tx[256], ty[256], tz[256], td[256];
  const int tid = threadIdx.x;
  const int wid = tid>>6, lane = tid&63;
  const int pid = blockIdx.x*4 + wid;     // b*NG+g
  const int b = pid >> 11;
  const float* bx = xs + b*NPTS;
  const float* by = ys + b*NPTS;
  const float* bz = zs + b*NPTS;
  const float* bD = d2 + b*NPTS;
  const int fi = fps_idx[pid];
  const float ax = bx[fi], ay = by[fi], az = bz[fi];
  const float src2 = __fadd_rn(__fadd_rn(__fmul_rn(ax,ax),__fmul_rn(ay,ay)),__fmul_rn(az,az));
  float Ad = INFINITY; int Ai = 0x7fffffff;      // sorted-ascending top-64 (1/lane)
  float tau_d = INFINITY; int tau_i = 0x7fffffff; // current exact 32nd smallest
  for (int s=0; s<NPTS/256; ++s){
    __syncthreads();
    int gidx = s*256 + tid;
    tx[tid]=bx[gidx]; ty[tid]=by[gidx]; tz[tid]=bz[gidx]; td[tid]=bD[gidx];
    __syncthreads();
    float m0,m1,m2,m3; int i0,i1,i2,i3;
#define LOADJ(mj, ij, J) { int li = (J)*64 + lane; \
    float dot = __fadd_rn(__fadd_rn(__fmul_rn(ax,tx[li]),__fmul_rn(ay,ty[li])),__fmul_rn(az,tz[li])); \
    mj = __fadd_rn(__fadd_rn(__fmul_rn(-2.0f,dot), src2), td[li]); ij = s*256 + li; }
    LOADJ(m0,i0,0) LOADJ(m1,i1,1) LOADJ(m2,i2,2) LOADJ(m3,i3,3)
#undef LOADJ
    while (true){
      bool any = lexlt(m0,i0,tau_d,tau_i) || lexlt(m1,i1,tau_d,tau_i) ||
                 lexlt(m2,i2,tau_d,tau_i) || lexlt(m3,i3,tau_d,tau_i);
      if (__ballot(any) == 0ull) break;
      float cd = m0; int ci = i0; int sel = 0;
      if (lexlt(m1,i1,cd,ci)){ cd=m1; ci=i1; sel=1; }
      if (lexlt(m2,i2,cd,ci)){ cd=m2; ci=i2; sel=2; }
      if (lexlt(m3,i3,cd,ci)){ cd=m3; ci=i3; sel=3; }
      if      (sel==0) m0=INFINITY;
      else if (sel==1) m1=INFINITY;
      else if (sel==2) m2=INFINITY;
      else             m3=INFINITY;
      sort_desc(cd, ci, lane);                    // new chunk descending
      if (lexlt(cd,ci,Ad,Ai)){ Ad=cd; Ai=ci; }    // elementwise min -> bitonic
      merge_asc(Ad, Ai, lane);                    // re-sort ascending
      tau_d = __shfl(Ad, 31);
      tau_i = __shfl(Ai, 31);
    }
  }
  if (lane < NK) knn_out[pid*NK + lane] = Ai;
}

// ---------------- global stats (fp64 partials per block) ----------------
__global__ __launch_bounds__(256) void stats_kernel(const float* __restrict__ x, const float* __restrict__ xyz,
                                                    const int* __restrict__ fps_idx, const int* __restrict__ knn,
                                                    double* __restrict__ partials){
  const int tid=threadIdx.x, wid=tid>>6, lane=tid&63;
  const int pid = blockIdx.x*4 + wid;
  const int b = pid>>11;
  const int fi = fps_idx[pid];
  const float* xb = x + (size_t)b*NPTS*CIN;
  const float* zb = xyz + (size_t)b*NPTS*3;
  const float lc0 = xb[fi*CIN + lane];
  float lc1 = 0.f; if (lane<32) lc1 = xb[fi*CIN + 64 + lane];
  float czv = 0.f; if (lane<3)  czv = zb[fi*3 + lane];
  double s1=0.0, s2=0.0, a1=0.0, a2=0.0;
  for (int k=0;k<NK;++k){
    int idx = knn[pid*NK + k];
    float d0 = __fsub_rn(xb[idx*CIN + lane], lc0);
    s1 += (double)d0; s2 += (double)d0*(double)d0;
    if (lane<32){
      float d1 = __fsub_rn(xb[idx*CIN + 64 + lane], lc1);
      s1 += (double)d1; s2 += (double)d1*(double)d1;
    }
    if (lane<3){
      float w = __fsub_rn(zb[idx*3 + lane], czv);
      a1 += (double)w; a2 += (double)w*(double)w;
    }
  }
#pragma unroll
  for (int off=32; off>0; off>>=1){ s1 += __shfl_xor(s1,off); s2 += __shfl_xor(s2,off); }
  __shared__ double shx[4][2];
  __shared__ double shz[4][3][2];
  if (lane==0){ shx[wid][0]=s1; shx[wid][1]=s2; }
  if (lane<3){ shz[wid][lane][0]=a1; shz[wid][lane][1]=a2; }
  __syncthreads();
  if (tid==0){
    double u0=0,u1=0;
    for (int w=0;w<4;++w){ u0+=shx[w][0]; u1+=shx[w][1]; }
    double* outp = partials + (size_t)blockIdx.x*8;
    outp[0]=u0; outp[1]=u1;
    for (int axq=0; axq<3; ++axq){
      double v0=0,v1=0;
      for (int w=0;w<4;++w){ v0+=shz[w][axq][0]; v1+=shz[w][axq][1]; }
      outp[2+2*axq]=v0; outp[3+2*axq]=v1;
    }
  }
}

__global__ void finalize_kernel(const double* __restrict__ partials, float* __restrict__ scal){
  const int lane = threadIdx.x;  // 64 threads, 1 wave
  double s1=0,s2=0;
  double z0a=0,z0b=0,z1a=0,z1b=0,z2a=0,z2b=0;
  for (int i=0;i<32;++i){
    const double* p = partials + (size_t)(lane*32+i)*8;   // 32 consecutive blocks -> same b
    s1+=p[0]; s2+=p[1];
    z0a+=p[2]; z0b+=p[3]; z1a+=p[4]; z1b+=p[5]; z2a+=p[6]; z2b+=p[7];
  }
#pragma unroll
  for (int off=32; off>0; off>>=1){ s1+=__shfl_xor(s1,off); s2+=__shfl_xor(s2,off); }
#pragma unroll
  for (int off=8; off>0; off>>=1){
    z0a+=__shfl_xor(z0a,off); z0b+=__shfl_xor(z0b,off);
    z1a+=__shfl_xor(z1a,off); z1b+=__shfl_xor(z1b,off);
    z2a+=__shfl_xor(z2a,off); z2b+=__shfl_xor(z2b,off);
  }
  __shared__ double zb[4][3][2];
  if ((lane&15)==0){
    int b = lane>>4;
    zb[b][0][0]=z0a; zb[b][0][1]=z0b;
    zb[b][1][0]=z1a; zb[b][1][1]=z1b;
    zb[b][2][0]=z2a; zb[b][2][1]=z2b;
  }
  __syncthreads();
  if (lane==0){
    double nx = (double)NB*NG*NK*CIN;
    double varx = (s2 - s1*s1/nx)/(nx-1.0);
    float stdx = (float)sqrt(varx);
    double t1=0,t2=0;
    for (int b=0;b<4;++b) for (int a=0;a<3;++a){ t1+=zb[b][a][0]; t2+=zb[b][a][1]; }
    double nz = (double)NB*NG*NK*3;
    double varz = (t2 - t1*t1/nz)/(nz-1.0);
    float stdz = (float)sqrt(varz);
    float sdiv = stdz + 1e-5f;
    double n2 = (double)NG*NK;
    double acc=0.0;
    for (int b=0;b<4;++b) for (int a=0;a<3;++a){
      double v = (zb[b][a][1] - zb[b][a][0]*zb[b][a][0]/n2)/(n2-1.0);
      acc += sqrt(v);
    }
    float gstd = (float)(acc/12.0) / sdiv;   // std(x4) = std(raw)/(std_xyz+1e-5)
    float sig = 0.26f*(1.0f+gstd) + 1e-6f;
    float blend = 1.0f/(1.0f + expf(-(gstd-0.1f)*10.0f));
    scal[0] = 1.0f/(stdx + 1e-5f);
    scal[1] = 1.0f/sdiv;
    scal[2] = 1.0f/sig;
    scal[3] = blend;
  }
}

// ---------------- main fused kernel: pe + weighting + max/mean over K -> lc in d_out ----------------
__global__ __launch_bounds__(256) void main_kernel(const float* __restrict__ x, const float* __restrict__ xyz,
                                                   const int* __restrict__ fps_idx, const int* __restrict__ knn,
                                                   const float* __restrict__ scal, float* __restrict__ lc_out){
  const int tid=threadIdx.x, wid=tid>>6, lane=tid&63;
  const int pid = blockIdx.x*4 + wid;
  const int b = pid>>11, g = pid&2047;
  const float inv_x = scal[0], inv_z = scal[1], inv_sig = scal[2], blend = scal[3];
  const float omb = 1.0f - blend;
  const int fi = fps_idx[pid];
  const float* xb = x + (size_t)b*NPTS*CIN;
  const float* zb = xyz + (size_t)b*NPTS*3;
  const float cx = zb[fi*3+0], cy = zb[fi*3+1], cz = zb[fi*3+2];
  // lane's 3 channels: c = lane, 64+lane, 128+lane
  const float lcx0 = xb[fi*CIN + lane];
  const float lcx1 = (lane<32) ? xb[fi*CIN + 64 + lane] : xb[fi*CIN + lane - 32];
  const float lcx2 = xb[fi*CIN + 32 + lane];
  // r0: fourier, dim = lane>>5 (0/1), rr = lane&31, freq = rr>>1, odd->cos
  const int dim0 = lane>>5;
  const int rr0 = lane&31;
  const bool cos0 = rr0 & 1;
  const float bs0 = 100.0f / powf(1000.0f, (float)(rr0>>1) * (1.0f/16.0f));
  // r1: lane<32 fourier dim=2; lane>=32 adaptive dim=0, j=lane-32
  const bool cos1 = lane & 1;
  const float bs1 = 100.0f / powf(1000.0f, (float)((lane&31)>>1) * (1.0f/16.0f));
  const float fv1 = (float)(-1.0 + 2.0*(double)(lane-32+1)/33.0);
  // r2: adaptive, cc=32+lane: dim=cc>>5 (1/2), j=cc&31
  const int dim2 = (32+lane)>>5;
  const int j2 = (32+lane)&31;
  const float fv2 = (float)(-1.0 + 2.0*(double)(j2+1)/33.0);

  float mx0=-INFINITY, mx1=-INFINITY, mx2=-INFINITY;
  float sm0=0.f, sm1=0.f, sm2=0.f;
  for (int k=0;k<NK;++k){
    const int idx = knn[pid*NK + k];
    const float p0 = zb[idx*3+0], p1 = zb[idx*3+1], p2v = zb[idx*3+2];
    const float xn0 = (p0-cx)*inv_z, xn1 = (p1-cy)*inv_z, xn2 = (p2v-cz)*inv_z;
    const float xk0 = xb[idx*CIN + lane];
    float xk1 = 0.f; if (lane<32) xk1 = xb[idx*CIN + 64 + lane];
    { // r0
      float v = dim0 ? xn1 : xn0;
      float a = v * bs0;
      float pe = cos0 ? __cosf(a) : __sinf(a);
      float f = (xk0 - lcx0) * inv_x;
      float w = (f + pe) * pe;
      mx0 = fmaxf(mx0, w); sm0 += w;
    }
    { // r1
      float pe, f;
      if (lane < 32){
        float a = xn2 * bs1;
        pe = cos1 ? __cosf(a) : __sinf(a);
        f = (xk1 - lcx1) * inv_x;
      } else {
        float zq = (xn0 - fv1) * inv_sig;
        pe = blend * __expf(-0.5f*zq*zq) + omb * __cosf(zq);
        f = lcx1;   // raw center features (second concat half)
      }
      float w = (f + pe) * pe;
      mx1 = fmaxf(mx1, w); sm1 += w;
    }
    { // r2
      float v = (dim2==1) ? xn1 : xn2;
      float zq = (v - fv2) * inv_sig;
      float pe = blend * __expf(-0.5f*zq*zq) + omb * __cosf(zq);
      float w = (lcx2 + pe) * pe;
      mx2 = fmaxf(mx2, w); sm2 += w;
    }
  }
  const size_t obase = ((size_t)b*COUT)*NG + g;
  lc_out[obase + (size_t)lane*NG]       = mx0 + sm0*(1.0f/32.0f);
  lc_out[obase + (size_t)(64+lane)*NG]  = mx1 + sm1*(1.0f/32.0f);
  lc_out[obase + (size_t)(128+lane)*NG] = mx2 + sm2*(1.0f/32.0f);
}

// ---------------- batch-norm stats (per channel over B,G; ddof=0) ----------------
__global__ __launch_bounds__(256) void bn_stats_kernel(const float* __restrict__ lc, float* __restrict__ bn){
  const int c = blockIdx.x, t = threadIdx.x, lane=t&63, wid=t>>6;
  double s1=0.0, s2=0.0;
  for (int i=t; i<NB*NG; i+=256){
    int b=i>>11, g=i&2047;
    float v = lc[((size_t)(b*COUT)+c)*NG + g];
    s1 += (double)v; s2 += (double)v*(double)v;
  }
#pragma unroll
  for (int off=32; off>0; off>>=1){ s1+=__shfl_xor(s1,off); s2+=__shfl_xor(s2,off); }
  __shared__ double sh1[4], sh2[4];
  if (lane==0){ sh1[wid]=s1; sh2[wid]=s2; }
  __syncthreads();
  if (t==0){
    double a=sh1[0]+sh1[1]+sh1[2]+sh1[3], q=sh2[0]+sh2[1]+sh2[2]+sh2[3];
    double n=(double)(NB*NG);
    double mu=a/n, var=q/n - mu*mu;
    bn[c]=(float)mu;
    bn[COUT+c]=(float)(1.0/sqrt(var + 1e-5));
  }
}

// ---------------- final: BN affine + exact gelu, in-place on d_out ----------------
__global__ __launch_bounds__(256) void final_kernel(const float* __restrict__ bn, const float* __restrict__ gamma,
                                                    const float* __restrict__ beta, float* __restrict__ out){
  int i = blockIdx.x*256 + threadIdx.x;
  int c = (i >> 11) % COUT;
  float v = out[i];
  float y = (v - bn[c]) * bn[COUT + c];
  y = y*gamma[c] + beta[c];
  out[i] = y * 0.5f * (1.0f + erff(y * 0.70710678118654752f));
}

extern "C" void kernel_launch(void* const* d_in, const int* in_sizes, int n_in,
                              void* d_out, int out_size, void* d_ws, size_t ws_size,
                              hipStream_t stream){
  const float* xyz   = (const float*)d_in[0];
  const float* x     = (const float*)d_in[1];
  const float* gamma = (const float*)d_in[2];
  const float* beta  = (const float*)d_in[3];
  float* out = (float*)d_out;
  char* ws = (char*)d_ws;
  // workspace layout (all regions fully written before read every launch)
  int*    fps  = (int*)   (ws + 0);        //  32 KB
  int*    knn  = (int*)   (ws + 32768);    //   1 MB
  float*  xs   = (float*) (ws + 1081344);  // 128 KB
  float*  ys   = (float*) (ws + 1212416);
  float*  zs   = (float*) (ws + 1343488);
  float*  d2   = (float*) (ws + 1474560);
  double* parts= (double*)(ws + 1605632);  // 2048*8 doubles
  float*  scal = (float*) (ws + 1736704);  // 4 floats
  float*  bn   = (float*) (ws + 1736768);  // 384 floats

  const int fps_lds = 131072 + 256 + 2048 + 384;   // ctab + keys[2][16] + hist + bbox scratch
  (void)hipFuncSetAttribute(reinterpret_cast<const void*>(fps_kernel),
                            hipFuncAttributeMaxDynamicSharedMemorySize, fps_lds);

  setup_kernel   <<<dim3((NB*NPTS+255)/256), dim3(256), 0, stream>>>(xyz, xs, ys, zs, d2);
  fps_kernel     <<<dim3(NB),                dim3(1024), fps_lds, stream>>>(xyz, fps);
  knn_kernel     <<<dim3(NB*NG/4),           dim3(256), 0, stream>>>(xs, ys, zs, d2, fps, knn);
  stats_kernel   <<<dim3(NB*NG/4),           dim3(256), 0, stream>>>(x, xyz, fps, knn, parts);
  finalize_kernel<<<dim3(1),                 dim3(64),  0, stream>>>(parts, scal);
  main_kernel    <<<dim3(NB*NG/4),           dim3(256), 0, stream>>>(x, xyz, fps, knn, scal, out);
  bn_stats_kernel<<<dim3(COUT),              dim3(256), 0, stream>>>(out, bn);
  final_kernel   <<<dim3((NB*COUT*NG)/256),  dim3(256), 0, stream>>>(bn, gamma, beta, out);
}

// Round 2
// 2914.908 us; speedup vs baseline: 1.0295x; 1.0295x over previous
//
#include <hip/hip_runtime.h>
#include <cstdint>
#include <math.h>

#define NPTS 8192
#define NB 4
#define NG 2048
#define NK 32
#define CIN 96
#define COUT 192

typedef unsigned long long ull;

// ---------------- setup: SoA transpose + |p|^2 (bit-exact vs ref dst2) ----------------
__global__ __launch_bounds__(256) void setup_kernel(const float* __restrict__ xyz,
                                                    float* __restrict__ xs, float* __restrict__ ys,
                                                    float* __restrict__ zs, float* __restrict__ d2){
  int i = blockIdx.x*256 + threadIdx.x;
  if (i >= NB*NPTS) return;
  float x = xyz[3*i+0], y = xyz[3*i+1], z = xyz[3*i+2];
  xs[i]=x; ys[i]=y; zs[i]=z;
  d2[i] = __fadd_rn(__fadd_rn(__fmul_rn(x,x),__fmul_rn(y,y)),__fmul_rn(z,z));
}

// Fused lexicographic (hi,lo) u64 max reduce step on the VALU pipe via DPP.
// hi = float bits of a non-negative distance (order-isomorphic to u32), lo = tie-break key.
template<int CTRL>
__device__ __forceinline__ void dppmax_pair(unsigned& hi, unsigned& lo){
  unsigned ohi = (unsigned)__builtin_amdgcn_update_dpp((int)hi, (int)hi, CTRL, 0xf, 0xf, false);
  unsigned olo = (unsigned)__builtin_amdgcn_update_dpp((int)lo, (int)lo, CTRL, 0xf, 0xf, false);
  bool gt = (ohi > hi) || (ohi == hi && olo > lo);
  hi = gt ? ohi : hi;
  lo = gt ? olo : lo;
}

__device__ __forceinline__ ull umax64(ull a, ull b){ return (a > b) ? a : b; }

// bbox lower bound on dist2(center, any point in box). Conservative vs fp error by the
// caller's 1e-4 relative margin (fma contraction here only perturbs by ~1ulp).
__device__ __forceinline__ float bbox_lb(float lx, float ly, float lz,
                                         float x0, float x1, float y0, float y1,
                                         float z0, float z1){
#pragma clang fp contract(off)
  float qx = fminf(fmaxf(lx,x0),x1);
  float qy = fminf(fmaxf(ly,y0),y1);
  float qz = fminf(fmaxf(lz,z0),z1);
  float dx = qx-lx, dy = qy-ly, dz = qz-lz;
  return (dx*dx+dy*dy)+dz*dz;
}

// ---------------- FPS: 512 threads, Morton-sorted points, 2-level bbox pruning -------
// 8 waves x 1024-pt Morton chunks; per wave two 512-pt half-bboxes. Registers hold only
// D[16]+lowb[16]; coordinates live in LDS ctab (read per active round). Per round:
// wave-level skip test (cheap common path); active path tests each half, updates only
// near halves, then ONE fused lex-(d,lowb) DPP chain to lane63. ONE barrier/round;
// all waves tree-reduce the 8 keys; coords via ctab broadcast read.
__global__ __launch_bounds__(512,2) void fps_kernel(const float* __restrict__ xyz, int* __restrict__ fps_idx){
#pragma clang fp contract(off)   // selection-critical: no fma contraction anywhere here
  extern __shared__ char smem[];
  float4* ctab = (float4*)smem;                          // 8192*16 = 131072 B
  ull*    keys = (ull*)(smem + 131072);                  // [2][8] = 128 B
  int*    hist = (int*)(smem + 131072 + 128);            // 512 cells = 2048 B
  float*  bbs  = (float*)(smem + 131072 + 128 + 2048);   // 8 waves * 6
  const int b = blockIdx.x, t = threadIdx.x;
  const int w = t>>6, lane = t&63;
  const float* base = xyz + (size_t)b*NPTS*3;

  // ---- init phase: load originals, global bbox, Morton cells, sort into ctab ----
  float ox[16], oy[16], oz[16];
#pragma unroll
  for (int j=0;j<16;++j){
    int p = t + 512*j;
    ox[j]=base[3*p+0]; oy[j]=base[3*p+1]; oz[j]=base[3*p+2];
  }
  float mnx=ox[0],mxx=ox[0],mny=oy[0],mxy=oy[0],mnz=oz[0],mxz=oz[0];
#pragma unroll
  for (int j=1;j<16;++j){
    mnx=fminf(mnx,ox[j]); mxx=fmaxf(mxx,ox[j]);
    mny=fminf(mny,oy[j]); mxy=fmaxf(mxy,oy[j]);
    mnz=fminf(mnz,oz[j]); mxz=fmaxf(mxz,oz[j]);
  }
#pragma unroll
  for (int off=32; off>0; off>>=1){
    mnx=fminf(mnx,__shfl_xor(mnx,off)); mxx=fmaxf(mxx,__shfl_xor(mxx,off));
    mny=fminf(mny,__shfl_xor(mny,off)); mxy=fmaxf(mxy,__shfl_xor(mxy,off));
    mnz=fminf(mnz,__shfl_xor(mnz,off)); mxz=fmaxf(mxz,__shfl_xor(mxz,off));
  }
  hist[t] = 0;
  if (lane==0){
    bbs[w*6+0]=mnx; bbs[w*6+1]=mxx; bbs[w*6+2]=mny;
    bbs[w*6+3]=mxy; bbs[w*6+4]=mnz; bbs[w*6+5]=mxz;
  }
  if (t==0) fps_idx[b*NG] = 0;
  __syncthreads();
  float gx0=1e30f,gx1=-1e30f,gy0=1e30f,gy1=-1e30f,gz0=1e30f,gz1=-1e30f;
  for (int q=0;q<8;++q){
    gx0=fminf(gx0,bbs[q*6+0]); gx1=fmaxf(gx1,bbs[q*6+1]);
    gy0=fminf(gy0,bbs[q*6+2]); gy1=fmaxf(gy1,bbs[q*6+3]);
    gz0=fminf(gz0,bbs[q*6+4]); gz1=fmaxf(gz1,bbs[q*6+5]);
  }
  const float sxv = 8.0f/fmaxf(gx1-gx0,1e-20f);
  const float syv = 8.0f/fmaxf(gy1-gy0,1e-20f);
  const float szv = 8.0f/fmaxf(gz1-gz0,1e-20f);
  int cell[16];
#pragma unroll
  for (int j=0;j<16;++j){
    int cx = min(7,(int)((ox[j]-gx0)*sxv));
    int cy = min(7,(int)((oy[j]-gy0)*syv));
    int cz = min(7,(int)((oz[j]-gz0)*szv));
    int m = (cx&1) | ((cy&1)<<1) | ((cz&1)<<2)
          | ((cx&2)<<2) | ((cy&2)<<3) | ((cz&2)<<4)
          | ((cx&4)<<4) | ((cy&4)<<5) | ((cz&4)<<6);
    cell[j]=m;
    atomicAdd(&hist[m],1);
  }
  __syncthreads();
  if (t < 64){    // wave-0 parallel exclusive prefix over 512 cells (8/lane)
    int s0[8];
#pragma unroll
    for (int j=0;j<8;++j) s0[j]=hist[t*8+j];
    int tot=0;
#pragma unroll
    for (int j=0;j<8;++j){ int v=s0[j]; s0[j]=tot; tot+=v; }
    int inc=tot;
#pragma unroll
    for (int off=1; off<64; off<<=1){
      int o=__shfl_up(inc,off);
      if (t>=off) inc+=o;
    }
    int excl=inc-tot;
#pragma unroll
    for (int j=0;j<8;++j) hist[t*8+j]=excl+s0[j];
  }
  __syncthreads();
#pragma unroll
  for (int j=0;j<16;++j){
    int pos = atomicAdd(&hist[cell[j]],1);
    ctab[pos] = make_float4(ox[j],oy[j],oz[j], __int_as_float(t+512*j));
  }
  __syncthreads();
  // reload sorted metadata: wave w owns positions w*1024 + j*64 + lane.
  // Registers: D[16] + lowb[16] only; coordinates stay in ctab (LDS).
  float D[16]; unsigned lowb[16];
  float hx0[2],hx1[2],hy0[2],hy1[2],hz0[2],hz1[2];
#pragma unroll
  for (int j=0;j<16;++j){
    int pos = (w<<10) + (j<<6) + lane;
    float4 c4 = ctab[pos];
    unsigned orig = (unsigned)__float_as_int(c4.w);
    lowb[j] = ((8191u-orig)<<13) | (unsigned)pos;   // max lowb == (max dist, lowest orig)
    D[j] = 1e10f;                                   // ref init
    const int h = j>>3;                             // compile-time in unrolled loop
    if ((j&7)==0){ hx0[h]=c4.x; hx1[h]=c4.x; hy0[h]=c4.y; hy1[h]=c4.y; hz0[h]=c4.z; hz1[h]=c4.z; }
    else {
      hx0[h]=fminf(hx0[h],c4.x); hx1[h]=fmaxf(hx1[h],c4.x);
      hy0[h]=fminf(hy0[h],c4.y); hy1[h]=fmaxf(hy1[h],c4.y);
      hz0[h]=fminf(hz0[h],c4.z); hz1[h]=fmaxf(hz1[h],c4.z);
    }
  }
#pragma unroll
  for (int h=0;h<2;++h){
#pragma unroll
    for (int off=32; off>0; off>>=1){
      hx0[h]=fminf(hx0[h],__shfl_xor(hx0[h],off)); hx1[h]=fmaxf(hx1[h],__shfl_xor(hx1[h],off));
      hy0[h]=fminf(hy0[h],__shfl_xor(hy0[h],off)); hy1[h]=fmaxf(hy1[h],__shfl_xor(hy1[h],off));
      hz0[h]=fminf(hz0[h],__shfl_xor(hz0[h],off)); hz1[h]=fmaxf(hz1[h],__shfl_xor(hz1[h],off));
    }
  }
  // wave-level bbox = union of halves
  const float bx0=fminf(hx0[0],hx0[1]), bx1=fmaxf(hx1[0],hx1[1]);
  const float by0=fminf(hy0[0],hy0[1]), by1=fmaxf(hy1[0],hy1[1]);
  const float bz0=fminf(hz0[0],hz0[1]), bz1=fmaxf(hz1[0],hz1[1]);

  // ---- serial rounds ----
  float lx=base[0], ly=base[1], lz=base[2];   // seed = point 0
  float Mw = 1e10f;                           // wave's current max D
  unsigned mylow = 0;                         // wave's cached key low32
  for (int it=0; it<NG-1; ++it){
    // exact-safe skip test: LB lower-bounds dist2(center, any owned point);
    // margin 1e-4 rel >> 3e-7 max fp error -> skip only when provably no D changes
    const float thr = Mw*1.0001f;
    float LB = bbox_lb(lx,ly,lz, bx0,bx1,by0,by1,bz0,bz1);
    ull* kslot = &keys[(it&1)*8 + w];
    if (LB <= thr){
      // half-level tests (conservative: Mw >= per-half max D, so skip is provably safe)
      float LB0 = bbox_lb(lx,ly,lz, hx0[0],hx1[0],hy0[0],hy1[0],hz0[0],hz1[0]);
      float LB1 = bbox_lb(lx,ly,lz, hx0[1],hx1[1],hy0[1],hy1[1],hz0[1],hz1[1]);
      if (LB0 <= thr){
#pragma unroll
        for (int j=0;j<8;++j){
          float4 c4 = ctab[(w<<10) + (j<<6) + lane];
          float dx=c4.x-lx, dy=c4.y-ly, dz=c4.z-lz;
          float d=(dx*dx+dy*dy)+dz*dz;
          D[j]=fminf(D[j],d);
        }
      }
      if (LB1 <= thr){
#pragma unroll
        for (int j=8;j<16;++j){
          float4 c4 = ctab[(w<<10) + (j<<6) + lane];
          float dx=c4.x-lx, dy=c4.y-ly, dz=c4.z-lz;
          float d=(dx*dx+dy*dy)+dz*dz;
          D[j]=fminf(D[j],d);
        }
      }
      float bd=-1.0f;
#pragma unroll
      for (int j=0;j<16;++j) bd=fmaxf(bd,D[j]);
      unsigned bl=0;
#pragma unroll
      for (int j=0;j<16;++j){
        unsigned c2 = (lowb[j]>bl)?lowb[j]:bl;
        bl = (D[j]==bd) ? c2 : bl;
      }
      // fused lexicographic (dist-bits, lowb) wave max -> lane 63
      unsigned hi = __float_as_uint(bd), lo = bl;
      dppmax_pair<0x111>(hi,lo); dppmax_pair<0x112>(hi,lo); dppmax_pair<0x114>(hi,lo);
      dppmax_pair<0x118>(hi,lo); dppmax_pair<0x142>(hi,lo); dppmax_pair<0x143>(hi,lo);
      unsigned hw  = (unsigned)__builtin_amdgcn_readlane((int)hi,63);
      unsigned lwv = (unsigned)__builtin_amdgcn_readlane((int)lo,63);
      if (lane==63) *kslot = (((ull)hw)<<32) | (ull)lwv;
      Mw = __uint_as_float(hw);
      mylow = lwv;
    } else {
      if (lane==63) *kslot = (((ull)__float_as_uint(Mw))<<32) | (ull)mylow;
    }
    __syncthreads();                              // ONE barrier per round
    const ulonglong2* kk2 = (const ulonglong2*)(keys + (it&1)*8);
    ulonglong2 p0 = kk2[0], p1 = kk2[1], p2 = kk2[2], p3 = kk2[3];
    ull a0 = umax64(p0.x, p0.y), a1 = umax64(p1.x, p1.y);
    ull a2 = umax64(p2.x, p2.y), a3 = umax64(p3.x, p3.y);
    ull k  = umax64(umax64(a0,a1), umax64(a2,a3));
    unsigned lw = (unsigned)k;
    float4 c4 = ctab[lw & 0x1FFFu];               // broadcast ds_read_b128
    lx=c4.x; ly=c4.y; lz=c4.z;
    if (t==0) fps_idx[b*NG + it + 1] = (int)(8191u - ((lw>>13)&0x1FFFu));
  }
}

// ---------------- kNN: wave-wide exact top-32 (lexicographic (d,idx)) ----------------
__device__ __forceinline__ bool lexlt(float ad, int ai, float bd, int bi){
  return (ad < bd) || ((ad == bd) && (ai < bi));
}
__device__ __forceinline__ void sort_desc(float& d, int& i, int lane){
#pragma unroll
  for (int k=2;k<=64;k<<=1){
#pragma unroll
    for (int j=k>>1;j>0;j>>=1){
      float od = __shfl_xor(d, j);
      int   oi = __shfl_xor(i, j);
      bool dirUp = (lane & k) != 0;      // flipped -> overall descending
      bool lower = (lane & j) == 0;
      bool less  = lexlt(d,i,od,oi);
      bool keep  = (less == (lower == dirUp));
      if (!keep){ d=od; i=oi; }
    }
  }
}
__device__ __forceinline__ void merge_asc(float& d, int& i, int lane){
#pragma unroll
  for (int j=32;j>0;j>>=1){
    float od = __shfl_xor(d, j);
    int   oi = __shfl_xor(i, j);
    bool lower = (lane & j) == 0;
    bool less  = lexlt(d,i,od,oi);
    bool keep  = (less == lower);
    if (!keep){ d=od; i=oi; }
  }
}

__global__ __launch_bounds__(256) void knn_kernel(const float* __restrict__ xs, const float* __restrict__ ys,
                                                  const float* __restrict__ zs, const float* __restrict__ d2,
                                                  const int* __restrict__ fps_idx, int* __restrict__ knn_out){
  __shared__ float tx[256], ty[256], tz[256], td[256];
  const int tid = threadIdx.x;
  const int wid = tid>>6, lane = tid&63;
  const int pid = blockIdx.x*4 + wid;     // b*NG+g
  const int b = pid >> 11;
  const float* bx = xs + b*NPTS;
  const float* by = ys + b*NPTS;
  const float* bz = zs + b*NPTS;
  const float* bD = d2 + b*NPTS;
  const int fi = fps_idx[pid];
  const float ax = bx[fi], ay = by[fi], az = bz[fi];
  const float src2 = __fadd_rn(__fadd_rn(__fmul_rn(ax,ax),__fmul_rn(ay,ay)),__fmul_rn(az,az));
  float Ad = INFINITY; int Ai = 0x7fffffff;      // sorted-ascending top-64 (1/lane)
  float tau_d = INFINITY; int tau_i = 0x7fffffff; // current exact 32nd smallest
  for (int s=0; s<NPTS/256; ++s){
    __syncthreads();
    int gidx = s*256 + tid;
    tx[tid]=bx[gidx]; ty[tid]=by[gidx]; tz[tid]=bz[gidx]; td[tid]=bD[gidx];
    __syncthreads();
    float m0,m1,m2,m3; int i0,i1,i2,i3;
#define LOADJ(mj, ij, J) { int li = (J)*64 + lane; \
    float dot = __fadd_rn(__fadd_rn(__fmul_rn(ax,tx[li]),__fmul_rn(ay,ty[li])),__fmul_rn(az,tz[li])); \
    mj = __fadd_rn(__fadd_rn(__fmul_rn(-2.0f,dot), src2), td[li]); ij = s*256 + li; }
    LOADJ(m0,i0,0) LOADJ(m1,i1,1) LOADJ(m2,i2,2) LOADJ(m3,i3,3)
#undef LOADJ
    while (true){
      bool any = lexlt(m0,i0,tau_d,tau_i) || lexlt(m1,i1,tau_d,tau_i) ||
                 lexlt(m2,i2,tau_d,tau_i) || lexlt(m3,i3,tau_d,tau_i);
      if (__ballot(any) == 0ull) break;
      float cd = m0; int ci = i0; int sel = 0;
      if (lexlt(m1,i1,cd,ci)){ cd=m1; ci=i1; sel=1; }
      if (lexlt(m2,i2,cd,ci)){ cd=m2; ci=i2; sel=2; }
      if (lexlt(m3,i3,cd,ci)){ cd=m3; ci=i3; sel=3; }
      if      (sel==0) m0=INFINITY;
      else if (sel==1) m1=INFINITY;
      else if (sel==2) m2=INFINITY;
      else             m3=INFINITY;
      sort_desc(cd, ci, lane);                    // new chunk descending
      if (lexlt(cd,ci,Ad,Ai)){ Ad=cd; Ai=ci; }    // elementwise min -> bitonic
      merge_asc(Ad, Ai, lane);                    // re-sort ascending
      tau_d = __shfl(Ad, 31);
      tau_i = __shfl(Ai, 31);
    }
  }
  if (lane < NK) knn_out[pid*NK + lane] = Ai;
}

// ---------------- global stats (fp64 partials per block) ----------------
__global__ __launch_bounds__(256) void stats_kernel(const float* __restrict__ x, const float* __restrict__ xyz,
                                                    const int* __restrict__ fps_idx, const int* __restrict__ knn,
                                                    double* __restrict__ partials){
  const int tid=threadIdx.x, wid=tid>>6, lane=tid&63;
  const int pid = blockIdx.x*4 + wid;
  const int b = pid>>11;
  const int fi = fps_idx[pid];
  const float* xb = x + (size_t)b*NPTS*CIN;
  const float* zb = xyz + (size_t)b*NPTS*3;
  const float lc0 = xb[fi*CIN + lane];
  float lc1 = 0.f; if (lane<32) lc1 = xb[fi*CIN + 64 + lane];
  float czv = 0.f; if (lane<3)  czv = zb[fi*3 + lane];
  double s1=0.0, s2=0.0, a1=0.0, a2=0.0;
  for (int k=0;k<NK;++k){
    int idx = knn[pid*NK + k];
    float d0 = __fsub_rn(xb[idx*CIN + lane], lc0);
    s1 += (double)d0; s2 += (double)d0*(double)d0;
    if (lane<32){
      float d1 = __fsub_rn(xb[idx*CIN + 64 + lane], lc1);
      s1 += (double)d1; s2 += (double)d1*(double)d1;
    }
    if (lane<3){
      float w = __fsub_rn(zb[idx*3 + lane], czv);
      a1 += (double)w; a2 += (double)w*(double)w;
    }
  }
#pragma unroll
  for (int off=32; off>0; off>>=1){ s1 += __shfl_xor(s1,off); s2 += __shfl_xor(s2,off); }
  __shared__ double shx[4][2];
  __shared__ double shz[4][3][2];
  if (lane==0){ shx[wid][0]=s1; shx[wid][1]=s2; }
  if (lane<3){ shz[wid][lane][0]=a1; shz[wid][lane][1]=a2; }
  __syncthreads();
  if (tid==0){
    double u0=0,u1=0;
    for (int w=0;w<4;++w){ u0+=shx[w][0]; u1+=shx[w][1]; }
    double* outp = partials + (size_t)blockIdx.x*8;
    outp[0]=u0; outp[1]=u1;
    for (int axq=0; axq<3; ++axq){
      double v0=0,v1=0;
      for (int w=0;w<4;++w){ v0+=shz[w][axq][0]; v1+=shz[w][axq][1]; }
      outp[2+2*axq]=v0; outp[3+2*axq]=v1;
    }
  }
}

__global__ void finalize_kernel(const double* __restrict__ partials, float* __restrict__ scal){
  const int lane = threadIdx.x;  // 64 threads, 1 wave
  double s1=0,s2=0;
  double z0a=0,z0b=0,z1a=0,z1b=0,z2a=0,z2b=0;
  for (int i=0;i<32;++i){
    const double* p = partials + (size_t)(lane*32+i)*8;   // 32 consecutive blocks -> same b
    s1+=p[0]; s2+=p[1];
    z0a+=p[2]; z0b+=p[3]; z1a+=p[4]; z1b+=p[5]; z2a+=p[6]; z2b+=p[7];
  }
#pragma unroll
  for (int off=32; off>0; off>>=1){ s1+=__shfl_xor(s1,off); s2+=__shfl_xor(s2,off); }
#pragma unroll
  for (int off=8; off>0; off>>=1){
    z0a+=__shfl_xor(z0a,off); z0b+=__shfl_xor(z0b,off);
    z1a+=__shfl_xor(z1a,off); z1b+=__shfl_xor(z1b,off);
    z2a+=__shfl_xor(z2a,off); z2b+=__shfl_xor(z2b,off);
  }
  __shared__ double zb[4][3][2];
  if ((lane&15)==0){
    int b = lane>>4;
    zb[b][0][0]=z0a; zb[b][0][1]=z0b;
    zb[b][1][0]=z1a; zb[b][1][1]=z1b;
    zb[b][2][0]=z2a; zb[b][2][1]=z2b;
  }
  __syncthreads();
  if (lane==0){
    double nx = (double)NB*NG*NK*CIN;
    double varx = (s2 - s1*s1/nx)/(nx-1.0);
    float stdx = (float)sqrt(varx);
    double t1=0,t2=0;
    for (int b=0;b<4;++b) for (int a=0;a<3;++a){ t1+=zb[b][a][0]; t2+=zb[b][a][1]; }
    double nz = (double)NB*NG*NK*3;
    double varz = (t2 - t1*t1/nz)/(nz-1.0);
    float stdz = (float)sqrt(varz);
    float sdiv = stdz + 1e-5f;
    double n2 = (double)NG*NK;
    double acc=0.0;
    for (int b=0;b<4;++b) for (int a=0;a<3;++a){
      double v = (zb[b][a][1] - zb[b][a][0]*zb[b][a][0]/n2)/(n2-1.0);
      acc += sqrt(v);
    }
    float gstd = (float)(acc/12.0) / sdiv;   // std(x4) = std(raw)/(std_xyz+1e-5)
    float sig = 0.26f*(1.0f+gstd) + 1e-6f;
    float blend = 1.0f/(1.0f + expf(-(gstd-0.1f)*10.0f));
    scal[0] = 1.0f/(stdx + 1e-5f);
    scal[1] = 1.0f/sdiv;
    scal[2] = 1.0f/sig;
    scal[3] = blend;
  }
}

// ---------------- main fused kernel: pe + weighting + max/mean over K -> lc in d_out ----------------
__global__ __launch_bounds__(256) void main_kernel(const float* __restrict__ x, const float* __restrict__ xyz,
                                                   const int* __restrict__ fps_idx, const int* __restrict__ knn,
                                                   const float* __restrict__ scal, float* __restrict__ lc_out){
  const int tid=threadIdx.x, wid=tid>>6, lane=tid&63;
  const int pid = blockIdx.x*4 + wid;
  const int b = pid>>11, g = pid&2047;
  const float inv_x = scal[0], inv_z = scal[1], inv_sig = scal[2], blend = scal[3];
  const float omb = 1.0f - blend;
  const int fi = fps_idx[pid];
  const float* xb = x + (size_t)b*NPTS*CIN;
  const float* zb = xyz + (size_t)b*NPTS*3;
  const float cx = zb[fi*3+0], cy = zb[fi*3+1], cz = zb[fi*3+2];
  // lane's 3 channels: c = lane, 64+lane, 128+lane
  const float lcx0 = xb[fi*CIN + lane];
  const float lcx1 = (lane<32) ? xb[fi*CIN + 64 + lane] : xb[fi*CIN + lane - 32];
  const float lcx2 = xb[fi*CIN + 32 + lane];
  // r0: fourier, dim = lane>>5 (0/1), rr = lane&31, freq = rr>>1, odd->cos
  const int dim0 = lane>>5;
  const int rr0 = lane&31;
  const bool cos0 = rr0 & 1;
  const float bs0 = 100.0f / powf(1000.0f, (float)(rr0>>1) * (1.0f/16.0f));
  // r1: lane<32 fourier dim=2; lane>=32 adaptive dim=0, j=lane-32
  const bool cos1 = lane & 1;
  const float bs1 = 100.0f / powf(1000.0f, (float)((lane&31)>>1) * (1.0f/16.0f));
  const float fv1 = (float)(-1.0 + 2.0*(double)(lane-32+1)/33.0);
  // r2: adaptive, cc=32+lane: dim=cc>>5 (1/2), j=cc&31
  const int dim2 = (32+lane)>>5;
  const int j2 = (32+lane)&31;
  const float fv2 = (float)(-1.0 + 2.0*(double)(j2+1)/33.0);

  float mx0=-INFINITY, mx1=-INFINITY, mx2=-INFINITY;
  float sm0=0.f, sm1=0.f, sm2=0.f;
  for (int k=0;k<NK;++k){
    const int idx = knn[pid*NK + k];
    const float p0 = zb[idx*3+0], p1 = zb[idx*3+1], p2v = zb[idx*3+2];
    const float xn0 = (p0-cx)*inv_z, xn1 = (p1-cy)*inv_z, xn2 = (p2v-cz)*inv_z;
    const float xk0 = xb[idx*CIN + lane];
    float xk1 = 0.f; if (lane<32) xk1 = xb[idx*CIN + 64 + lane];
    { // r0
      float v = dim0 ? xn1 : xn0;
      float a = v * bs0;
      float pe = cos0 ? __cosf(a) : __sinf(a);
      float f = (xk0 - lcx0) * inv_x;
      float w = (f + pe) * pe;
      mx0 = fmaxf(mx0, w); sm0 += w;
    }
    { // r1
      float pe, f;
      if (lane < 32){
        float a = xn2 * bs1;
        pe = cos1 ? __cosf(a) : __sinf(a);
        f = (xk1 - lcx1) * inv_x;
      } else {
        float zq = (xn0 - fv1) * inv_sig;
        pe = blend * __expf(-0.5f*zq*zq) + omb * __cosf(zq);
        f = lcx1;   // raw center features (second concat half)
      }
      float w = (f + pe) * pe;
      mx1 = fmaxf(mx1, w); sm1 += w;
    }
    { // r2
      float v = (dim2==1) ? xn1 : xn2;
      float zq = (v - fv2) * inv_sig;
      float pe = blend * __expf(-0.5f*zq*zq) + omb * __cosf(zq);
      float w = (lcx2 + pe) * pe;
      mx2 = fmaxf(mx2, w); sm2 += w;
    }
  }
  const size_t obase = ((size_t)b*COUT)*NG + g;
  lc_out[obase + (size_t)lane*NG]       = mx0 + sm0*(1.0f/32.0f);
  lc_out[obase + (size_t)(64+lane)*NG]  = mx1 + sm1*(1.0f/32.0f);
  lc_out[obase + (size_t)(128+lane)*NG] = mx2 + sm2*(1.0f/32.0f);
}

// ---------------- batch-norm stats (per channel over B,G; ddof=0) ----------------
__global__ __launch_bounds__(256) void bn_stats_kernel(const float* __restrict__ lc, float* __restrict__ bn){
  const int c = blockIdx.x, t = threadIdx.x, lane=t&63, wid=t>>6;
  double s1=0.0, s2=0.0;
  for (int i=t; i<NB*NG; i+=256){
    int b=i>>11, g=i&2047;
    float v = lc[((size_t)(b*COUT)+c)*NG + g];
    s1 += (double)v; s2 += (double)v*(double)v;
  }
#pragma unroll
  for (int off=32; off>0; off>>=1){ s1+=__shfl_xor(s1,off); s2+=__shfl_xor(s2,off); }
  __shared__ double sh1[4], sh2[4];
  if (lane==0){ sh1[wid]=s1; sh2[wid]=s2; }
  __syncthreads();
  if (t==0){
    double a=sh1[0]+sh1[1]+sh1[2]+sh1[3], q=sh2[0]+sh2[1]+sh2[2]+sh2[3];
    double n=(double)(NB*NG);
    double mu=a/n, var=q/n - mu*mu;
    bn[c]=(float)mu;
    bn[COUT+c]=(float)(1.0/sqrt(var + 1e-5));
  }
}

// ---------------- final: BN affine + exact gelu, in-place on d_out ----------------
__global__ __launch_bounds__(256) void final_kernel(const float* __restrict__ bn, const float* __restrict__ gamma,
                                                    const float* __restrict__ beta, float* __restrict__ out){
  int i = blockIdx.x*256 + threadIdx.x;
  int c = (i >> 11) % COUT;
  float v = out[i];
  float y = (v - bn[c]) * bn[COUT + c];
  y = y*gamma[c] + beta[c];
  out[i] = y * 0.5f * (1.0f + erff(y * 0.70710678118654752f));
}

extern "C" void kernel_launch(void* const* d_in, const int* in_sizes, int n_in,
                              void* d_out, int out_size, void* d_ws, size_t ws_size,
                              hipStream_t stream){
  const float* xyz   = (const float*)d_in[0];
  const float* x     = (const float*)d_in[1];
  const float* gamma = (const float*)d_in[2];
  const float* beta  = (const float*)d_in[3];
  float* out = (float*)d_out;
  char* ws = (char*)d_ws;
  // workspace layout (all regions fully written before read every launch)
  int*    fps  = (int*)   (ws + 0);        //  32 KB
  int*    knn  = (int*)   (ws + 32768);    //   1 MB
  float*  xs   = (float*) (ws + 1081344);  // 128 KB
  float*  ys   = (float*) (ws + 1212416);
  float*  zs   = (float*) (ws + 1343488);
  float*  d2   = (float*) (ws + 1474560);
  double* parts= (double*)(ws + 1605632);  // 2048*8 doubles
  float*  scal = (float*) (ws + 1736704);  // 4 floats
  float*  bn   = (float*) (ws + 1736768);  // 384 floats

  const int fps_lds = 131072 + 128 + 2048 + 192;   // ctab + keys[2][8] + hist + bbox scratch
  (void)hipFuncSetAttribute(reinterpret_cast<const void*>(fps_kernel),
                            hipFuncAttributeMaxDynamicSharedMemorySize, fps_lds);

  setup_kernel   <<<dim3((NB*NPTS+255)/256), dim3(256), 0, stream>>>(xyz, xs, ys, zs, d2);
  fps_kernel     <<<dim3(NB),                dim3(512), fps_lds, stream>>>(xyz, fps);
  knn_kernel     <<<dim3(NB*NG/4),           dim3(256), 0, stream>>>(xs, ys, zs, d2, fps, knn);
  stats_kernel   <<<dim3(NB*NG/4),           dim3(256), 0, stream>>>(x, xyz, fps, knn, parts);
  finalize_kernel<<<dim3(1),                 dim3(64),  0, stream>>>(parts, scal);
  main_kernel    <<<dim3(NB*NG/4),           dim3(256), 0, stream>>>(x, xyz, fps, knn, scal, out);
  bn_stats_kernel<<<dim3(COUT),              dim3(256), 0, stream>>>(out, bn);
  final_kernel   <<<dim3((NB*COUT*NG)/256),  dim3(256), 0, stream>>>(bn, gamma, beta, out);
}

// Round 3
// 2611.124 us; speedup vs baseline: 1.1492x; 1.1163x over previous
//
#include <hip/hip_runtime.h>
#include <cstdint>
#include <math.h>

#define NPTS 8192
#define NB 4
#define NG 2048
#define NK 32
#define CIN 96
#define COUT 192

typedef unsigned long long ull;

// ---------------- setup: SoA transpose + |p|^2 (bit-exact vs ref dst2) ----------------
__global__ __launch_bounds__(256) void setup_kernel(const float* __restrict__ xyz,
                                                    float* __restrict__ xs, float* __restrict__ ys,
                                                    float* __restrict__ zs, float* __restrict__ d2){
  int i = blockIdx.x*256 + threadIdx.x;
  if (i >= NB*NPTS) return;
  float x = xyz[3*i+0], y = xyz[3*i+1], z = xyz[3*i+2];
  xs[i]=x; ys[i]=y; zs[i]=z;
  d2[i] = __fadd_rn(__fadd_rn(__fmul_rn(x,x),__fmul_rn(y,y)),__fmul_rn(z,z));
}

// Fused lexicographic (hi,lo) u64 max reduce step on the VALU pipe via DPP.
// hi = float bits of a non-negative distance (order-isomorphic to u32), lo = tie-break key.
template<int CTRL>
__device__ __forceinline__ void dppmax_pair(unsigned& hi, unsigned& lo){
  unsigned ohi = (unsigned)__builtin_amdgcn_update_dpp((int)hi, (int)hi, CTRL, 0xf, 0xf, false);
  unsigned olo = (unsigned)__builtin_amdgcn_update_dpp((int)lo, (int)lo, CTRL, 0xf, 0xf, false);
  bool gt = (ohi > hi) || (ohi == hi && olo > lo);
  hi = gt ? ohi : hi;
  lo = gt ? olo : lo;
}

__device__ __forceinline__ ull umax64(ull a, ull b){ return (a > b) ? a : b; }

// bbox lower bound on dist2(center, any point in box). Conservative vs fp error by the
// caller's 1e-4 relative margin.
__device__ __forceinline__ float bbox_lb(float lx, float ly, float lz,
                                         float x0, float x1, float y0, float y1,
                                         float z0, float z1){
#pragma clang fp contract(off)
  float qx = fminf(fmaxf(lx,x0),x1);
  float qy = fminf(fmaxf(ly,y0),y1);
  float qz = fminf(fmaxf(lz,z0),z1);
  float dx = qx-lx, dy = qy-ly, dz = qz-lz;
  return (dx*dx+dy*dy)+dz*dz;
}

// ---------------- FPS: 512 threads, Morton-sorted, register coords, 2-level pruning ----
// 8 waves x 1024-pt Morton chunks; coords/D/lowb fully register-resident (the round-0
// configuration). Per wave: two 512-pt half-bboxes with CACHED per-half candidates
// (Mh, Lh). A skipped half's D is untouched -> cache stays valid -> its update loop,
// max-tree and lowb scan are all skipped. Only active halves recompute. Wave candidate =
// lexmax of the two half candidates -> ONE fused lex-(d,lowb) DPP chain to lane63.
// ONE barrier/round; all waves tree-reduce the 8 keys; coords via ctab broadcast read.
__global__ __launch_bounds__(512,2) void fps_kernel(const float* __restrict__ xyz, int* __restrict__ fps_idx){
#pragma clang fp contract(off)   // selection-critical: no fma contraction anywhere here
  extern __shared__ char smem[];
  float4* ctab = (float4*)smem;                          // 8192*16 = 131072 B
  ull*    keys = (ull*)(smem + 131072);                  // [2][8] = 128 B
  int*    hist = (int*)(smem + 131072 + 128);            // 512 cells = 2048 B
  float*  bbs  = (float*)(smem + 131072 + 128 + 2048);   // 8 waves * 6
  const int b = blockIdx.x, t = threadIdx.x;
  const int w = t>>6, lane = t&63;
  const float* base = xyz + (size_t)b*NPTS*3;

  // ---- init phase: load originals, global bbox, Morton cells, sort into ctab ----
  float ox[16], oy[16], oz[16];
#pragma unroll
  for (int j=0;j<16;++j){
    int p = t + 512*j;
    ox[j]=base[3*p+0]; oy[j]=base[3*p+1]; oz[j]=base[3*p+2];
  }
  float mnx=ox[0],mxx=ox[0],mny=oy[0],mxy=oy[0],mnz=oz[0],mxz=oz[0];
#pragma unroll
  for (int j=1;j<16;++j){
    mnx=fminf(mnx,ox[j]); mxx=fmaxf(mxx,ox[j]);
    mny=fminf(mny,oy[j]); mxy=fmaxf(mxy,oy[j]);
    mnz=fminf(mnz,oz[j]); mxz=fmaxf(mxz,oz[j]);
  }
#pragma unroll
  for (int off=32; off>0; off>>=1){
    mnx=fminf(mnx,__shfl_xor(mnx,off)); mxx=fmaxf(mxx,__shfl_xor(mxx,off));
    mny=fminf(mny,__shfl_xor(mny,off)); mxy=fmaxf(mxy,__shfl_xor(mxy,off));
    mnz=fminf(mnz,__shfl_xor(mnz,off)); mxz=fmaxf(mxz,__shfl_xor(mxz,off));
  }
  hist[t] = 0;
  if (lane==0){
    bbs[w*6+0]=mnx; bbs[w*6+1]=mxx; bbs[w*6+2]=mny;
    bbs[w*6+3]=mxy; bbs[w*6+4]=mnz; bbs[w*6+5]=mxz;
  }
  if (t==0) fps_idx[b*NG] = 0;
  __syncthreads();
  float gx0=1e30f,gx1=-1e30f,gy0=1e30f,gy1=-1e30f,gz0=1e30f,gz1=-1e30f;
  for (int q=0;q<8;++q){
    gx0=fminf(gx0,bbs[q*6+0]); gx1=fmaxf(gx1,bbs[q*6+1]);
    gy0=fminf(gy0,bbs[q*6+2]); gy1=fmaxf(gy1,bbs[q*6+3]);
    gz0=fminf(gz0,bbs[q*6+4]); gz1=fmaxf(gz1,bbs[q*6+5]);
  }
  const float sxv = 8.0f/fmaxf(gx1-gx0,1e-20f);
  const float syv = 8.0f/fmaxf(gy1-gy0,1e-20f);
  const float szv = 8.0f/fmaxf(gz1-gz0,1e-20f);
  int cell[16];
#pragma unroll
  for (int j=0;j<16;++j){
    int cx = min(7,(int)((ox[j]-gx0)*sxv));
    int cy = min(7,(int)((oy[j]-gy0)*syv));
    int cz = min(7,(int)((oz[j]-gz0)*szv));
    int m = (cx&1) | ((cy&1)<<1) | ((cz&1)<<2)
          | ((cx&2)<<2) | ((cy&2)<<3) | ((cz&2)<<4)
          | ((cx&4)<<4) | ((cy&4)<<5) | ((cz&4)<<6);
    cell[j]=m;
    atomicAdd(&hist[m],1);
  }
  __syncthreads();
  if (t < 64){    // wave-0 parallel exclusive prefix over 512 cells (8/lane)
    int s0[8];
#pragma unroll
    for (int j=0;j<8;++j) s0[j]=hist[t*8+j];
    int tot=0;
#pragma unroll
    for (int j=0;j<8;++j){ int v=s0[j]; s0[j]=tot; tot+=v; }
    int inc=tot;
#pragma unroll
    for (int off=1; off<64; off<<=1){
      int o=__shfl_up(inc,off);
      if (t>=off) inc+=o;
    }
    int excl=inc-tot;
#pragma unroll
    for (int j=0;j<8;++j) hist[t*8+j]=excl+s0[j];
  }
  __syncthreads();
#pragma unroll
  for (int j=0;j<16;++j){
    int pos = atomicAdd(&hist[cell[j]],1);
    ctab[pos] = make_float4(ox[j],oy[j],oz[j], __int_as_float(t+512*j));
  }
  __syncthreads();
  // reload sorted: wave w owns positions w*1024 + j*64 + lane; all state in registers.
  float px[16],py[16],pz[16],D[16]; unsigned lowb[16];
  float hx0[2],hx1[2],hy0[2],hy1[2],hz0[2],hz1[2];
#pragma unroll
  for (int j=0;j<16;++j){
    int pos = (w<<10) + (j<<6) + lane;
    float4 c4 = ctab[pos];
    px[j]=c4.x; py[j]=c4.y; pz[j]=c4.z;
    unsigned orig = (unsigned)__float_as_int(c4.w);
    lowb[j] = ((8191u-orig)<<13) | (unsigned)pos;   // max lowb == (max dist, lowest orig)
    D[j] = 1e10f;                                   // ref init
    const int h = j>>3;                             // compile-time in unrolled loop
    if ((j&7)==0){ hx0[h]=c4.x; hx1[h]=c4.x; hy0[h]=c4.y; hy1[h]=c4.y; hz0[h]=c4.z; hz1[h]=c4.z; }
    else {
      hx0[h]=fminf(hx0[h],c4.x); hx1[h]=fmaxf(hx1[h],c4.x);
      hy0[h]=fminf(hy0[h],c4.y); hy1[h]=fmaxf(hy1[h],c4.y);
      hz0[h]=fminf(hz0[h],c4.z); hz1[h]=fmaxf(hz1[h],c4.z);
    }
  }
#pragma unroll
  for (int h=0;h<2;++h){
#pragma unroll
    for (int off=32; off>0; off>>=1){
      hx0[h]=fminf(hx0[h],__shfl_xor(hx0[h],off)); hx1[h]=fmaxf(hx1[h],__shfl_xor(hx1[h],off));
      hy0[h]=fminf(hy0[h],__shfl_xor(hy0[h],off)); hy1[h]=fmaxf(hy1[h],__shfl_xor(hy1[h],off));
      hz0[h]=fminf(hz0[h],__shfl_xor(hz0[h],off)); hz1[h]=fmaxf(hz1[h],__shfl_xor(hz1[h],off));
    }
  }
  // wave-level bbox = union of halves
  const float bx0=fminf(hx0[0],hx0[1]), bx1=fmaxf(hx1[0],hx1[1]);
  const float by0=fminf(hy0[0],hy0[1]), by1=fmaxf(hy1[0],hy1[1]);
  const float bz0=fminf(hz0[0],hz0[1]), bz1=fmaxf(hz1[0],hz1[1]);

  // cached per-half candidates: valid whenever the half's D is untouched.
  float M0v = 1e10f, M1v = 1e10f;        // all D equal -> Lh = max lowb in half
  unsigned L0v = 0, L1v = 0;
#pragma unroll
  for (int j=0;j<8;++j){
    L0v = (lowb[j]   > L0v) ? lowb[j]   : L0v;
    L1v = (lowb[j+8] > L1v) ? lowb[j+8] : L1v;
  }

  // ---- serial rounds ----
  float lx=base[0], ly=base[1], lz=base[2];   // seed = point 0
  float Mw = 1e10f;                           // wave's current max D (post-DPP)
  unsigned mylow = 0;                         // wave's cached key low32
  for (int it=0; it<NG-1; ++it){
    // exact-safe skip test: LB lower-bounds dist2(center, any owned point);
    // margin 1e-4 rel >> 3e-7 max fp error -> skip only when provably no D changes
    const float thr = Mw*1.0001f;
    float LB = bbox_lb(lx,ly,lz, bx0,bx1,by0,by1,bz0,bz1);
    ull* kslot = &keys[(it&1)*8 + w];
    bool wrote_new = false;
    if (LB <= thr){
      // half-level tests (safe: thr >= Mh*1.0001, so LB_h > thr proves no D change in half)
      float LB0 = bbox_lb(lx,ly,lz, hx0[0],hx1[0],hy0[0],hy1[0],hz0[0],hz1[0]);
      float LB1 = bbox_lb(lx,ly,lz, hx0[1],hx1[1],hy0[1],hy1[1],hz0[1],hz1[1]);
      const bool a0 = (LB0 <= thr), a1 = (LB1 <= thr);   // wave-uniform
      if (a0 || a1){
        if (a0){
          float m = -1.0f;
#pragma unroll
          for (int j=0;j<8;++j){
            float dx=px[j]-lx, dy=py[j]-ly, dz=pz[j]-lz;
            float d=(dx*dx+dy*dy)+dz*dz;
            float nd=fminf(D[j],d);
            D[j]=nd;
            m=fmaxf(m,nd);
          }
          unsigned L=0;
#pragma unroll
          for (int j=0;j<8;++j){
            unsigned c2 = (lowb[j]>L)?lowb[j]:L;
            L = (D[j]==m) ? c2 : L;
          }
          M0v=m; L0v=L;
        }
        if (a1){
          float m = -1.0f;
#pragma unroll
          for (int j=8;j<16;++j){
            float dx=px[j]-lx, dy=py[j]-ly, dz=pz[j]-lz;
            float d=(dx*dx+dy*dy)+dz*dz;
            float nd=fminf(D[j],d);
            D[j]=nd;
            m=fmaxf(m,nd);
          }
          unsigned L=0;
#pragma unroll
          for (int j=8;j<16;++j){
            unsigned c2 = (lowb[j]>L)?lowb[j]:L;
            L = (D[j]==m) ? c2 : L;
          }
          M1v=m; L1v=L;
        }
        // lane candidate = lexmax of half candidates (identical to 16-wide selection)
        unsigned hi0=__float_as_uint(M0v), hi1=__float_as_uint(M1v);
        bool g1 = (hi1>hi0) || (hi1==hi0 && L1v>L0v);
        unsigned hi = g1?hi1:hi0;
        unsigned lo = g1?L1v:L0v;
        // fused lexicographic (dist-bits, lowb) wave max -> lane 63
        dppmax_pair<0x111>(hi,lo); dppmax_pair<0x112>(hi,lo); dppmax_pair<0x114>(hi,lo);
        dppmax_pair<0x118>(hi,lo); dppmax_pair<0x142>(hi,lo); dppmax_pair<0x143>(hi,lo);
        unsigned hw  = (unsigned)__builtin_amdgcn_readlane((int)hi,63);
        unsigned lwv = (unsigned)__builtin_amdgcn_readlane((int)lo,63);
        if (lane==63) *kslot = (((ull)hw)<<32) | (ull)lwv;
        Mw = __uint_as_float(hw);
        mylow = lwv;
        wrote_new = true;
      }
    }
    if (!wrote_new){
      if (lane==63) *kslot = (((ull)__float_as_uint(Mw))<<32) | (ull)mylow;
    }
    __syncthreads();                              // ONE barrier per round
    const ulonglong2* kk2 = (const ulonglong2*)(keys + (it&1)*8);
    ulonglong2 p0 = kk2[0], p1 = kk2[1], p2 = kk2[2], p3 = kk2[3];
    ull a0k = umax64(p0.x, p0.y), a1k = umax64(p1.x, p1.y);
    ull a2k = umax64(p2.x, p2.y), a3k = umax64(p3.x, p3.y);
    ull k  = umax64(umax64(a0k,a1k), umax64(a2k,a3k));
    unsigned lw = (unsigned)k;
    float4 c4 = ctab[lw & 0x1FFFu];               // broadcast ds_read_b128
    lx=c4.x; ly=c4.y; lz=c4.z;
    if (t==0) fps_idx[b*NG + it + 1] = (int)(8191u - ((lw>>13)&0x1FFFu));
  }
}

// ---------------- kNN: wave-wide exact top-32 (lexicographic (d,idx)) ----------------
__device__ __forceinline__ bool lexlt(float ad, int ai, float bd, int bi){
  return (ad < bd) || ((ad == bd) && (ai < bi));
}
__device__ __forceinline__ void sort_desc(float& d, int& i, int lane){
#pragma unroll
  for (int k=2;k<=64;k<<=1){
#pragma unroll
    for (int j=k>>1;j>0;j>>=1){
      float od = __shfl_xor(d, j);
      int   oi = __shfl_xor(i, j);
      bool dirUp = (lane & k) != 0;      // flipped -> overall descending
      bool lower = (lane & j) == 0;
      bool less  = lexlt(d,i,od,oi);
      bool keep  = (less == (lower == dirUp));
      if (!keep){ d=od; i=oi; }
    }
  }
}
__device__ __forceinline__ void merge_asc(float& d, int& i, int lane){
#pragma unroll
  for (int j=32;j>0;j>>=1){
    float od = __shfl_xor(d, j);
    int   oi = __shfl_xor(i, j);
    bool lower = (lane & j) == 0;
    bool less  = lexlt(d,i,od,oi);
    bool keep  = (less == lower);
    if (!keep){ d=od; i=oi; }
  }
}

__global__ __launch_bounds__(256) void knn_kernel(const float* __restrict__ xs, const float* __restrict__ ys,
                                                  const float* __restrict__ zs, const float* __restrict__ d2,
                                                  const int* __restrict__ fps_idx, int* __restrict__ knn_out){
  __shared__ float tx[256], ty[256], tz[256], td[256];
  const int tid = threadIdx.x;
  const int wid = tid>>6, lane = tid&63;
  const int pid = blockIdx.x*4 + wid;     // b*NG+g
  const int b = pid >> 11;
  const float* bx = xs + b*NPTS;
  const float* by = ys + b*NPTS;
  const float* bz = zs + b*NPTS;
  const float* bD = d2 + b*NPTS;
  const int fi = fps_idx[pid];
  const float ax = bx[fi], ay = by[fi], az = bz[fi];
  const float src2 = __fadd_rn(__fadd_rn(__fmul_rn(ax,ax),__fmul_rn(ay,ay)),__fmul_rn(az,az));
  float Ad = INFINITY; int Ai = 0x7fffffff;      // sorted-ascending top-64 (1/lane)
  float tau_d = INFINITY; int tau_i = 0x7fffffff; // current exact 32nd smallest
  for (int s=0; s<NPTS/256; ++s){
    __syncthreads();
    int gidx = s*256 + tid;
    tx[tid]=bx[gidx]; ty[tid]=by[gidx]; tz[tid]=bz[gidx]; td[tid]=bD[gidx];
    __syncthreads();
    float m0,m1,m2,m3; int i0,i1,i2,i3;
#define LOADJ(mj, ij, J) { int li = (J)*64 + lane; \
    float dot = __fadd_rn(__fadd_rn(__fmul_rn(ax,tx[li]),__fmul_rn(ay,ty[li])),__fmul_rn(az,tz[li])); \
    mj = __fadd_rn(__fadd_rn(__fmul_rn(-2.0f,dot), src2), td[li]); ij = s*256 + li; }
    LOADJ(m0,i0,0) LOADJ(m1,i1,1) LOADJ(m2,i2,2) LOADJ(m3,i3,3)
#undef LOADJ
    while (true){
      bool any = lexlt(m0,i0,tau_d,tau_i) || lexlt(m1,i1,tau_d,tau_i) ||
                 lexlt(m2,i2,tau_d,tau_i) || lexlt(m3,i3,tau_d,tau_i);
      if (__ballot(any) == 0ull) break;
      float cd = m0; int ci = i0; int sel = 0;
      if (lexlt(m1,i1,cd,ci)){ cd=m1; ci=i1; sel=1; }
      if (lexlt(m2,i2,cd,ci)){ cd=m2; ci=i2; sel=2; }
      if (lexlt(m3,i3,cd,ci)){ cd=m3; ci=i3; sel=3; }
      if      (sel==0) m0=INFINITY;
      else if (sel==1) m1=INFINITY;
      else if (sel==2) m2=INFINITY;
      else             m3=INFINITY;
      sort_desc(cd, ci, lane);                    // new chunk descending
      if (lexlt(cd,ci,Ad,Ai)){ Ad=cd; Ai=ci; }    // elementwise min -> bitonic
      merge_asc(Ad, Ai, lane);                    // re-sort ascending
      tau_d = __shfl(Ad, 31);
      tau_i = __shfl(Ai, 31);
    }
  }
  if (lane < NK) knn_out[pid*NK + lane] = Ai;
}

// ---------------- global stats (fp64 partials per block) ----------------
__global__ __launch_bounds__(256) void stats_kernel(const float* __restrict__ x, const float* __restrict__ xyz,
                                                    const int* __restrict__ fps_idx, const int* __restrict__ knn,
                                                    double* __restrict__ partials){
  const int tid=threadIdx.x, wid=tid>>6, lane=tid&63;
  const int pid = blockIdx.x*4 + wid;
  const int b = pid>>11;
  const int fi = fps_idx[pid];
  const float* xb = x + (size_t)b*NPTS*CIN;
  const float* zb = xyz + (size_t)b*NPTS*3;
  const float lc0 = xb[fi*CIN + lane];
  float lc1 = 0.f; if (lane<32) lc1 = xb[fi*CIN + 64 + lane];
  float czv = 0.f; if (lane<3)  czv = zb[fi*3 + lane];
  double s1=0.0, s2=0.0, a1=0.0, a2=0.0;
  for (int k=0;k<NK;++k){
    int idx = knn[pid*NK + k];
    float d0 = __fsub_rn(xb[idx*CIN + lane], lc0);
    s1 += (double)d0; s2 += (double)d0*(double)d0;
    if (lane<32){
      float d1 = __fsub_rn(xb[idx*CIN + 64 + lane], lc1);
      s1 += (double)d1; s2 += (double)d1*(double)d1;
    }
    if (lane<3){
      float w = __fsub_rn(zb[idx*3 + lane], czv);
      a1 += (double)w; a2 += (double)w*(double)w;
    }
  }
#pragma unroll
  for (int off=32; off>0; off>>=1){ s1 += __shfl_xor(s1,off); s2 += __shfl_xor(s2,off); }
  __shared__ double shx[4][2];
  __shared__ double shz[4][3][2];
  if (lane==0){ shx[wid][0]=s1; shx[wid][1]=s2; }
  if (lane<3){ shz[wid][lane][0]=a1; shz[wid][lane][1]=a2; }
  __syncthreads();
  if (tid==0){
    double u0=0,u1=0;
    for (int w=0;w<4;++w){ u0+=shx[w][0]; u1+=shx[w][1]; }
    double* outp = partials + (size_t)blockIdx.x*8;
    outp[0]=u0; outp[1]=u1;
    for (int axq=0; axq<3; ++axq){
      double v0=0,v1=0;
      for (int w=0;w<4;++w){ v0+=shz[w][axq][0]; v1+=shz[w][axq][1]; }
      outp[2+2*axq]=v0; outp[3+2*axq]=v1;
    }
  }
}

__global__ void finalize_kernel(const double* __restrict__ partials, float* __restrict__ scal){
  const int lane = threadIdx.x;  // 64 threads, 1 wave
  double s1=0,s2=0;
  double z0a=0,z0b=0,z1a=0,z1b=0,z2a=0,z2b=0;
  for (int i=0;i<32;++i){
    const double* p = partials + (size_t)(lane*32+i)*8;   // 32 consecutive blocks -> same b
    s1+=p[0]; s2+=p[1];
    z0a+=p[2]; z0b+=p[3]; z1a+=p[4]; z1b+=p[5]; z2a+=p[6]; z2b+=p[7];
  }
#pragma unroll
  for (int off=32; off>0; off>>=1){ s1+=__shfl_xor(s1,off); s2+=__shfl_xor(s2,off); }
#pragma unroll
  for (int off=8; off>0; off>>=1){
    z0a+=__shfl_xor(z0a,off); z0b+=__shfl_xor(z0b,off);
    z1a+=__shfl_xor(z1a,off); z1b+=__shfl_xor(z1b,off);
    z2a+=__shfl_xor(z2a,off); z2b+=__shfl_xor(z2b,off);
  }
  __shared__ double zb[4][3][2];
  if ((lane&15)==0){
    int b = lane>>4;
    zb[b][0][0]=z0a; zb[b][0][1]=z0b;
    zb[b][1][0]=z1a; zb[b][1][1]=z1b;
    zb[b][2][0]=z2a; zb[b][2][1]=z2b;
  }
  __syncthreads();
  if (lane==0){
    double nx = (double)NB*NG*NK*CIN;
    double varx = (s2 - s1*s1/nx)/(nx-1.0);
    float stdx = (float)sqrt(varx);
    double t1=0,t2=0;
    for (int b=0;b<4;++b) for (int a=0;a<3;++a){ t1+=zb[b][a][0]; t2+=zb[b][a][1]; }
    double nz = (double)NB*NG*NK*3;
    double varz = (t2 - t1*t1/nz)/(nz-1.0);
    float stdz = (float)sqrt(varz);
    float sdiv = stdz + 1e-5f;
    double n2 = (double)NG*NK;
    double acc=0.0;
    for (int b=0;b<4;++b) for (int a=0;a<3;++a){
      double v = (zb[b][a][1] - zb[b][a][0]*zb[b][a][0]/n2)/(n2-1.0);
      acc += sqrt(v);
    }
    float gstd = (float)(acc/12.0) / sdiv;   // std(x4) = std(raw)/(std_xyz+1e-5)
    float sig = 0.26f*(1.0f+gstd) + 1e-6f;
    float blend = 1.0f/(1.0f + expf(-(gstd-0.1f)*10.0f));
    scal[0] = 1.0f/(stdx + 1e-5f);
    scal[1] = 1.0f/sdiv;
    scal[2] = 1.0f/sig;
    scal[3] = blend;
  }
}

// ---------------- main fused kernel: pe + weighting + max/mean over K -> lc in d_out ----------------
__global__ __launch_bounds__(256) void main_kernel(const float* __restrict__ x, const float* __restrict__ xyz,
                                                   const int* __restrict__ fps_idx, const int* __restrict__ knn,
                                                   const float* __restrict__ scal, float* __restrict__ lc_out){
  const int tid=threadIdx.x, wid=tid>>6, lane=tid&63;
  const int pid = blockIdx.x*4 + wid;
  const int b = pid>>11, g = pid&2047;
  const float inv_x = scal[0], inv_z = scal[1], inv_sig = scal[2], blend = scal[3];
  const float omb = 1.0f - blend;
  const int fi = fps_idx[pid];
  const float* xb = x + (size_t)b*NPTS*CIN;
  const float* zb = xyz + (size_t)b*NPTS*3;
  const float cx = zb[fi*3+0], cy = zb[fi*3+1], cz = zb[fi*3+2];
  // lane's 3 channels: c = lane, 64+lane, 128+lane
  const float lcx0 = xb[fi*CIN + lane];
  const float lcx1 = (lane<32) ? xb[fi*CIN + 64 + lane] : xb[fi*CIN + lane - 32];
  const float lcx2 = xb[fi*CIN + 32 + lane];
  // r0: fourier, dim = lane>>5 (0/1), rr = lane&31, freq = rr>>1, odd->cos
  const int dim0 = lane>>5;
  const int rr0 = lane&31;
  const bool cos0 = rr0 & 1;
  const float bs0 = 100.0f / powf(1000.0f, (float)(rr0>>1) * (1.0f/16.0f));
  // r1: lane<32 fourier dim=2; lane>=32 adaptive dim=0, j=lane-32
  const bool cos1 = lane & 1;
  const float bs1 = 100.0f / powf(1000.0f, (float)((lane&31)>>1) * (1.0f/16.0f));
  const float fv1 = (float)(-1.0 + 2.0*(double)(lane-32+1)/33.0);
  // r2: adaptive, cc=32+lane: dim=cc>>5 (1/2), j=cc&31
  const int dim2 = (32+lane)>>5;
  const int j2 = (32+lane)&31;
  const float fv2 = (float)(-1.0 + 2.0*(double)(j2+1)/33.0);

  float mx0=-INFINITY, mx1=-INFINITY, mx2=-INFINITY;
  float sm0=0.f, sm1=0.f, sm2=0.f;
  for (int k=0;k<NK;++k){
    const int idx = knn[pid*NK + k];
    const float p0 = zb[idx*3+0], p1 = zb[idx*3+1], p2v = zb[idx*3+2];
    const float xn0 = (p0-cx)*inv_z, xn1 = (p1-cy)*inv_z, xn2 = (p2v-cz)*inv_z;
    const float xk0 = xb[idx*CIN + lane];
    float xk1 = 0.f; if (lane<32) xk1 = xb[idx*CIN + 64 + lane];
    { // r0
      float v = dim0 ? xn1 : xn0;
      float a = v * bs0;
      float pe = cos0 ? __cosf(a) : __sinf(a);
      float f = (xk0 - lcx0) * inv_x;
      float w = (f + pe) * pe;
      mx0 = fmaxf(mx0, w); sm0 += w;
    }
    { // r1
      float pe, f;
      if (lane < 32){
        float a = xn2 * bs1;
        pe = cos1 ? __cosf(a) : __sinf(a);
        f = (xk1 - lcx1) * inv_x;
      } else {
        float zq = (xn0 - fv1) * inv_sig;
        pe = blend * __expf(-0.5f*zq*zq) + omb * __cosf(zq);
        f = lcx1;   // raw center features (second concat half)
      }
      float w = (f + pe) * pe;
      mx1 = fmaxf(mx1, w); sm1 += w;
    }
    { // r2
      float v = (dim2==1) ? xn1 : xn2;
      float zq = (v - fv2) * inv_sig;
      float pe = blend * __expf(-0.5f*zq*zq) + omb * __cosf(zq);
      float w = (lcx2 + pe) * pe;
      mx2 = fmaxf(mx2, w); sm2 += w;
    }
  }
  const size_t obase = ((size_t)b*COUT)*NG + g;
  lc_out[obase + (size_t)lane*NG]       = mx0 + sm0*(1.0f/32.0f);
  lc_out[obase + (size_t)(64+lane)*NG]  = mx1 + sm1*(1.0f/32.0f);
  lc_out[obase + (size_t)(128+lane)*NG] = mx2 + sm2*(1.0f/32.0f);
}

// ---------------- batch-norm stats (per channel over B,G; ddof=0) ----------------
__global__ __launch_bounds__(256) void bn_stats_kernel(const float* __restrict__ lc, float* __restrict__ bn){
  const int c = blockIdx.x, t = threadIdx.x, lane=t&63, wid=t>>6;
  double s1=0.0, s2=0.0;
  for (int i=t; i<NB*NG; i+=256){
    int b=i>>11, g=i&2047;
    float v = lc[((size_t)(b*COUT)+c)*NG + g];
    s1 += (double)v; s2 += (double)v*(double)v;
  }
#pragma unroll
  for (int off=32; off>0; off>>=1){ s1+=__shfl_xor(s1,off); s2+=__shfl_xor(s2,off); }
  __shared__ double sh1[4], sh2[4];
  if (lane==0){ sh1[wid]=s1; sh2[wid]=s2; }
  __syncthreads();
  if (t==0){
    double a=sh1[0]+sh1[1]+sh1[2]+sh1[3], q=sh2[0]+sh2[1]+sh2[2]+sh2[3];
    double n=(double)(NB*NG);
    double mu=a/n, var=q/n - mu*mu;
    bn[c]=(float)mu;
    bn[COUT+c]=(float)(1.0/sqrt(var + 1e-5));
  }
}

// ---------------- final: BN affine + exact gelu, in-place on d_out ----------------
__global__ __launch_bounds__(256) void final_kernel(const float* __restrict__ bn, const float* __restrict__ gamma,
                                                    const float* __restrict__ beta, float* __restrict__ out){
  int i = blockIdx.x*256 + threadIdx.x;
  int c = (i >> 11) % COUT;
  float v = out[i];
  float y = (v - bn[c]) * bn[COUT + c];
  y = y*gamma[c] + beta[c];
  out[i] = y * 0.5f * (1.0f + erff(y * 0.70710678118654752f));
}

extern "C" void kernel_launch(void* const* d_in, const int* in_sizes, int n_in,
                              void* d_out, int out_size, void* d_ws, size_t ws_size,
                              hipStream_t stream){
  const float* xyz   = (const float*)d_in[0];
  const float* x     = (const float*)d_in[1];
  const float* gamma = (const float*)d_in[2];
  const float* beta  = (const float*)d_in[3];
  float* out = (float*)d_out;
  char* ws = (char*)d_ws;
  // workspace layout (all regions fully written before read every launch)
  int*    fps  = (int*)   (ws + 0);        //  32 KB
  int*    knn  = (int*)   (ws + 32768);    //   1 MB
  float*  xs   = (float*) (ws + 1081344);  // 128 KB
  float*  ys   = (float*) (ws + 1212416);
  float*  zs   = (float*) (ws + 1343488);
  float*  d2   = (float*) (ws + 1474560);
  double* parts= (double*)(ws + 1605632);  // 2048*8 doubles
  float*  scal = (float*) (ws + 1736704);  // 4 floats
  float*  bn   = (float*) (ws + 1736768);  // 384 floats

  const int fps_lds = 131072 + 128 + 2048 + 192;   // ctab + keys[2][8] + hist + bbox scratch
  (void)hipFuncSetAttribute(reinterpret_cast<const void*>(fps_kernel),
                            hipFuncAttributeMaxDynamicSharedMemorySize, fps_lds);

  setup_kernel   <<<dim3((NB*NPTS+255)/256), dim3(256), 0, stream>>>(xyz, xs, ys, zs, d2);
  fps_kernel     <<<dim3(NB),                dim3(512), fps_lds, stream>>>(xyz, fps);
  knn_kernel     <<<dim3(NB*NG/4),           dim3(256), 0, stream>>>(xs, ys, zs, d2, fps, knn);
  stats_kernel   <<<dim3(NB*NG/4),           dim3(256), 0, stream>>>(x, xyz, fps, knn, parts);
  finalize_kernel<<<dim3(1),                 dim3(64),  0, stream>>>(parts, scal);
  main_kernel    <<<dim3(NB*NG/4),           dim3(256), 0, stream>>>(x, xyz, fps, knn, scal, out);
  bn_stats_kernel<<<dim3(COUT),              dim3(256), 0, stream>>>(out, bn);
  final_kernel   <<<dim3((NB*COUT*NG)/256),  dim3(256), 0, stream>>>(bn, gamma, beta, out);
}

// Round 4
// 2461.308 us; speedup vs baseline: 1.2192x; 1.0609x over previous
//
#include <hip/hip_runtime.h>
#include <cstdint>
#include <math.h>

#define NPTS 8192
#define NB 4
#define NG 2048
#define NK 32
#define CIN 96
#define COUT 192

typedef unsigned long long ull;

// ---------------- setup: SoA transpose + |p|^2 (bit-exact vs ref dst2) ----------------
__global__ __launch_bounds__(256) void setup_kernel(const float* __restrict__ xyz,
                                                    float* __restrict__ xs, float* __restrict__ ys,
                                                    float* __restrict__ zs, float* __restrict__ d2){
  int i = blockIdx.x*256 + threadIdx.x;
  if (i >= NB*NPTS) return;
  float x = xyz[3*i+0], y = xyz[3*i+1], z = xyz[3*i+2];
  xs[i]=x; ys[i]=y; zs[i]=z;
  d2[i] = __fadd_rn(__fadd_rn(__fmul_rn(x,x),__fmul_rn(y,y)),__fmul_rn(z,z));
}

// Fused lexicographic (hi,lo) u64 max reduce step on the VALU pipe via DPP.
// hi = float bits of a non-negative distance (order-isomorphic to u32), lo = tie-break key.
template<int CTRL>
__device__ __forceinline__ void dppmax_pair(unsigned& hi, unsigned& lo){
  unsigned ohi = (unsigned)__builtin_amdgcn_update_dpp((int)hi, (int)hi, CTRL, 0xf, 0xf, false);
  unsigned olo = (unsigned)__builtin_amdgcn_update_dpp((int)lo, (int)lo, CTRL, 0xf, 0xf, false);
  bool gt = (ohi > hi) || (ohi == hi && olo > lo);
  hi = gt ? ohi : hi;
  lo = gt ? olo : lo;
}

__device__ __forceinline__ ull umax64(ull a, ull b){ return (a > b) ? a : b; }

// ---------------- FPS: 512 threads, Morton-sorted, register coords (r0 structure) -----
// 8 waves x 1024-pt Morton chunks; coords/D/lowb fully register-resident, packed as
// float2 pairs so the backend can form v_pk_* f32 ops (per-component IEEE-identical to
// scalar). Per round: wave bbox skip test; active path = flat 16-pt update + ONE fused
// lex-(d,lowb) DPP chain to lane63. ONE barrier/round; depth-3 u64 tree over the 8 keys;
// coords via ctab broadcast read.
__global__ __launch_bounds__(512,2) void fps_kernel(const float* __restrict__ xyz, int* __restrict__ fps_idx){
#pragma clang fp contract(off)   // selection-critical: no fma contraction anywhere here
  extern __shared__ char smem[];
  float4* ctab = (float4*)smem;                          // 8192*16 = 131072 B
  ull*    keys = (ull*)(smem + 131072);                  // [2][8] = 128 B
  int*    hist = (int*)(smem + 131072 + 128);            // 512 cells = 2048 B
  float*  bbs  = (float*)(smem + 131072 + 128 + 2048);   // 8 waves * 6
  const int b = blockIdx.x, t = threadIdx.x;
  const int w = t>>6, lane = t&63;
  const float* base = xyz + (size_t)b*NPTS*3;

  // ---- init phase: load originals, global bbox, Morton cells, sort into ctab ----
  float ox[16], oy[16], oz[16];
#pragma unroll
  for (int j=0;j<16;++j){
    int p = t + 512*j;
    ox[j]=base[3*p+0]; oy[j]=base[3*p+1]; oz[j]=base[3*p+2];
  }
  float mnx=ox[0],mxx=ox[0],mny=oy[0],mxy=oy[0],mnz=oz[0],mxz=oz[0];
#pragma unroll
  for (int j=1;j<16;++j){
    mnx=fminf(mnx,ox[j]); mxx=fmaxf(mxx,ox[j]);
    mny=fminf(mny,oy[j]); mxy=fmaxf(mxy,oy[j]);
    mnz=fminf(mnz,oz[j]); mxz=fmaxf(mxz,oz[j]);
  }
#pragma unroll
  for (int off=32; off>0; off>>=1){
    mnx=fminf(mnx,__shfl_xor(mnx,off)); mxx=fmaxf(mxx,__shfl_xor(mxx,off));
    mny=fminf(mny,__shfl_xor(mny,off)); mxy=fmaxf(mxy,__shfl_xor(mxy,off));
    mnz=fminf(mnz,__shfl_xor(mnz,off)); mxz=fmaxf(mxz,__shfl_xor(mxz,off));
  }
  hist[t] = 0;
  if (lane==0){
    bbs[w*6+0]=mnx; bbs[w*6+1]=mxx; bbs[w*6+2]=mny;
    bbs[w*6+3]=mxy; bbs[w*6+4]=mnz; bbs[w*6+5]=mxz;
  }
  if (t==0) fps_idx[b*NG] = 0;
  __syncthreads();
  float gx0=1e30f,gx1=-1e30f,gy0=1e30f,gy1=-1e30f,gz0=1e30f,gz1=-1e30f;
  for (int q=0;q<8;++q){
    gx0=fminf(gx0,bbs[q*6+0]); gx1=fmaxf(gx1,bbs[q*6+1]);
    gy0=fminf(gy0,bbs[q*6+2]); gy1=fmaxf(gy1,bbs[q*6+3]);
    gz0=fminf(gz0,bbs[q*6+4]); gz1=fmaxf(gz1,bbs[q*6+5]);
  }
  const float sxv = 8.0f/fmaxf(gx1-gx0,1e-20f);
  const float syv = 8.0f/fmaxf(gy1-gy0,1e-20f);
  const float szv = 8.0f/fmaxf(gz1-gz0,1e-20f);
  int cell[16];
#pragma unroll
  for (int j=0;j<16;++j){
    int cx = min(7,(int)((ox[j]-gx0)*sxv));
    int cy = min(7,(int)((oy[j]-gy0)*syv));
    int cz = min(7,(int)((oz[j]-gz0)*szv));
    int m = (cx&1) | ((cy&1)<<1) | ((cz&1)<<2)
          | ((cx&2)<<2) | ((cy&2)<<3) | ((cz&2)<<4)
          | ((cx&4)<<4) | ((cy&4)<<5) | ((cz&4)<<6);
    cell[j]=m;
    atomicAdd(&hist[m],1);
  }
  __syncthreads();
  if (t < 64){    // wave-0 parallel exclusive prefix over 512 cells (8/lane)
    int s0[8];
#pragma unroll
    for (int j=0;j<8;++j) s0[j]=hist[t*8+j];
    int tot=0;
#pragma unroll
    for (int j=0;j<8;++j){ int v=s0[j]; s0[j]=tot; tot+=v; }
    int inc=tot;
#pragma unroll
    for (int off=1; off<64; off<<=1){
      int o=__shfl_up(inc,off);
      if (t>=off) inc+=o;
    }
    int excl=inc-tot;
#pragma unroll
    for (int j=0;j<8;++j) hist[t*8+j]=excl+s0[j];
  }
  __syncthreads();
#pragma unroll
  for (int j=0;j<16;++j){
    int pos = atomicAdd(&hist[cell[j]],1);
    ctab[pos] = make_float4(ox[j],oy[j],oz[j], __int_as_float(t+512*j));
  }
  __syncthreads();
  // reload sorted: wave w owns positions w*1024 + j*64 + lane; all state in registers,
  // coords packed as float2 pairs (point 2i -> .x, point 2i+1 -> .y).
  float2 px2[8], py2[8], pz2[8], D2[8];
  unsigned lowb[16];
  float bx0,bx1,by0,by1,bz0,bz1;
#pragma unroll
  for (int j=0;j<16;++j){
    int pos = (w<<10) + (j<<6) + lane;
    float4 c4 = ctab[pos];
    if ((j&1)==0){ px2[j>>1].x=c4.x; py2[j>>1].x=c4.y; pz2[j>>1].x=c4.z; D2[j>>1].x=1e10f; }
    else         { px2[j>>1].y=c4.x; py2[j>>1].y=c4.y; pz2[j>>1].y=c4.z; D2[j>>1].y=1e10f; }
    unsigned orig = (unsigned)__float_as_int(c4.w);
    lowb[j] = ((8191u-orig)<<13) | (unsigned)pos;   // max lowb == (max dist, lowest orig)
    if (j==0){ bx0=c4.x; bx1=c4.x; by0=c4.y; by1=c4.y; bz0=c4.z; bz1=c4.z; }
    else {
      bx0=fminf(bx0,c4.x); bx1=fmaxf(bx1,c4.x);
      by0=fminf(by0,c4.y); by1=fmaxf(by1,c4.y);
      bz0=fminf(bz0,c4.z); bz1=fmaxf(bz1,c4.z);
    }
  }
#pragma unroll
  for (int off=32; off>0; off>>=1){
    bx0=fminf(bx0,__shfl_xor(bx0,off)); bx1=fmaxf(bx1,__shfl_xor(bx1,off));
    by0=fminf(by0,__shfl_xor(by0,off)); by1=fmaxf(by1,__shfl_xor(by1,off));
    bz0=fminf(bz0,__shfl_xor(bz0,off)); bz1=fmaxf(bz1,__shfl_xor(bz1,off));
  }

  // ---- serial rounds ----
  float lx=base[0], ly=base[1], lz=base[2];   // seed = point 0
  float Mw = 1e10f;                           // wave's current max D
  unsigned mylow = 0;                         // wave's cached key low32
  for (int it=0; it<NG-1; ++it){
    // exact-safe skip test: LB lower-bounds dist2(center, any owned point);
    // margin 1e-4 rel >> 3e-7 max fp error -> skip only when provably no D changes
    float qx=fminf(fmaxf(lx,bx0),bx1);
    float qy=fminf(fmaxf(ly,by0),by1);
    float qz=fminf(fmaxf(lz,bz0),bz1);
    float ddx=qx-lx, ddy=qy-ly, ddz=qz-lz;
    float LB = (ddx*ddx+ddy*ddy)+ddz*ddz;
    ull* kslot = &keys[(it&1)*8 + w];
    if (LB <= Mw*1.0001f){
      // flat 16-pt update, float2-packed (per-component IEEE == scalar version)
      float2 bd2; bd2.x=-1.0f; bd2.y=-1.0f;
#pragma unroll
      for (int j=0;j<8;++j){
        float2 dx, dy, dz, d, nd;
        dx.x=px2[j].x-lx; dx.y=px2[j].y-lx;
        dy.x=py2[j].x-ly; dy.y=py2[j].y-ly;
        dz.x=pz2[j].x-lz; dz.y=pz2[j].y-lz;
        d.x=(dx.x*dx.x+dy.x*dy.x)+dz.x*dz.x;
        d.y=(dx.y*dx.y+dy.y*dy.y)+dz.y*dz.y;
        nd.x=fminf(D2[j].x,d.x); nd.y=fminf(D2[j].y,d.y);
        D2[j]=nd;
        bd2.x=fmaxf(bd2.x,nd.x); bd2.y=fmaxf(bd2.y,nd.y);
      }
      float bd = fmaxf(bd2.x, bd2.y);
      unsigned bl=0;
#pragma unroll
      for (int j=0;j<16;++j){
        float Dj = (j&1) ? D2[j>>1].y : D2[j>>1].x;
        unsigned c2 = (lowb[j]>bl)?lowb[j]:bl;
        bl = (Dj==bd) ? c2 : bl;
      }
      // fused lexicographic (dist-bits, lowb) wave max -> lane 63
      unsigned hi = __float_as_uint(bd), lo = bl;
      dppmax_pair<0x111>(hi,lo); dppmax_pair<0x112>(hi,lo); dppmax_pair<0x114>(hi,lo);
      dppmax_pair<0x118>(hi,lo); dppmax_pair<0x142>(hi,lo); dppmax_pair<0x143>(hi,lo);
      unsigned hw  = (unsigned)__builtin_amdgcn_readlane((int)hi,63);
      unsigned lwv = (unsigned)__builtin_amdgcn_readlane((int)lo,63);
      if (lane==63) *kslot = (((ull)hw)<<32) | (ull)lwv;
      Mw = __uint_as_float(hw);
      mylow = lwv;
    } else {
      if (lane==63) *kslot = (((ull)__float_as_uint(Mw))<<32) | (ull)mylow;
    }
    __syncthreads();                              // ONE barrier per round
    const ulonglong2* kk2 = (const ulonglong2*)(keys + (it&1)*8);
    ulonglong2 p0 = kk2[0], p1 = kk2[1], p2 = kk2[2], p3 = kk2[3];
    ull a0 = umax64(p0.x, p0.y), a1 = umax64(p1.x, p1.y);
    ull a2 = umax64(p2.x, p2.y), a3 = umax64(p3.x, p3.y);
    ull k  = umax64(umax64(a0,a1), umax64(a2,a3));
    unsigned lw = (unsigned)k;
    float4 c4 = ctab[lw & 0x1FFFu];               // broadcast ds_read_b128
    lx=c4.x; ly=c4.y; lz=c4.z;
    if (t==0) fps_idx[b*NG + it + 1] = (int)(8191u - ((lw>>13)&0x1FFFu));
  }
}

// ---------------- kNN: wave-wide exact top-32 (lexicographic (d,idx)) ----------------
__device__ __forceinline__ bool lexlt(float ad, int ai, float bd, int bi){
  return (ad < bd) || ((ad == bd) && (ai < bi));
}
__device__ __forceinline__ void sort_desc(float& d, int& i, int lane){
#pragma unroll
  for (int k=2;k<=64;k<<=1){
#pragma unroll
    for (int j=k>>1;j>0;j>>=1){
      float od = __shfl_xor(d, j);
      int   oi = __shfl_xor(i, j);
      bool dirUp = (lane & k) != 0;      // flipped -> overall descending
      bool lower = (lane & j) == 0;
      bool less  = lexlt(d,i,od,oi);
      bool keep  = (less == (lower == dirUp));
      if (!keep){ d=od; i=oi; }
    }
  }
}
__device__ __forceinline__ void merge_asc(float& d, int& i, int lane){
#pragma unroll
  for (int j=32;j>0;j>>=1){
    float od = __shfl_xor(d, j);
    int   oi = __shfl_xor(i, j);
    bool lower = (lane & j) == 0;
    bool less  = lexlt(d,i,od,oi);
    bool keep  = (less == lower);
    if (!keep){ d=od; i=oi; }
  }
}

__global__ __launch_bounds__(256) void knn_kernel(const float* __restrict__ xs, const float* __restrict__ ys,
                                                  const float* __restrict__ zs, const float* __restrict__ d2,
                                                  const int* __restrict__ fps_idx, int* __restrict__ knn_out){
  __shared__ float tx[256], ty[256], tz[256], td[256];
  const int tid = threadIdx.x;
  const int wid = tid>>6, lane = tid&63;
  const int pid = blockIdx.x*4 + wid;     // b*NG+g
  const int b = pid >> 11;
  const float* bx = xs + b*NPTS;
  const float* by = ys + b*NPTS;
  const float* bz = zs + b*NPTS;
  const float* bD = d2 + b*NPTS;
  const int fi = fps_idx[pid];
  const float ax = bx[fi], ay = by[fi], az = bz[fi];
  const float src2 = __fadd_rn(__fadd_rn(__fmul_rn(ax,ax),__fmul_rn(ay,ay)),__fmul_rn(az,az));
  float Ad = INFINITY; int Ai = 0x7fffffff;      // sorted-ascending top-64 (1/lane)
  float tau_d = INFINITY; int tau_i = 0x7fffffff; // current exact 32nd smallest
  for (int s=0; s<NPTS/256; ++s){
    __syncthreads();
    int gidx = s*256 + tid;
    tx[tid]=bx[gidx]; ty[tid]=by[gidx]; tz[tid]=bz[gidx]; td[tid]=bD[gidx];
    __syncthreads();
    float m0,m1,m2,m3; int i0,i1,i2,i3;
#define LOADJ(mj, ij, J) { int li = (J)*64 + lane; \
    float dot = __fadd_rn(__fadd_rn(__fmul_rn(ax,tx[li]),__fmul_rn(ay,ty[li])),__fmul_rn(az,tz[li])); \
    mj = __fadd_rn(__fadd_rn(__fmul_rn(-2.0f,dot), src2), td[li]); ij = s*256 + li; }
    LOADJ(m0,i0,0) LOADJ(m1,i1,1) LOADJ(m2,i2,2) LOADJ(m3,i3,3)
#undef LOADJ
    while (true){
      bool any = lexlt(m0,i0,tau_d,tau_i) || lexlt(m1,i1,tau_d,tau_i) ||
                 lexlt(m2,i2,tau_d,tau_i) || lexlt(m3,i3,tau_d,tau_i);
      if (__ballot(any) == 0ull) break;
      float cd = m0; int ci = i0; int sel = 0;
      if (lexlt(m1,i1,cd,ci)){ cd=m1; ci=i1; sel=1; }
      if (lexlt(m2,i2,cd,ci)){ cd=m2; ci=i2; sel=2; }
      if (lexlt(m3,i3,cd,ci)){ cd=m3; ci=i3; sel=3; }
      if      (sel==0) m0=INFINITY;
      else if (sel==1) m1=INFINITY;
      else if (sel==2) m2=INFINITY;
      else             m3=INFINITY;
      sort_desc(cd, ci, lane);                    // new chunk descending
      if (lexlt(cd,ci,Ad,Ai)){ Ad=cd; Ai=ci; }    // elementwise min -> bitonic
      merge_asc(Ad, Ai, lane);                    // re-sort ascending
      tau_d = __shfl(Ad, 31);
      tau_i = __shfl(Ai, 31);
    }
  }
  if (lane < NK) knn_out[pid*NK + lane] = Ai;
}

// ---------------- global stats (fp64 partials per block) ----------------
__global__ __launch_bounds__(256) void stats_kernel(const float* __restrict__ x, const float* __restrict__ xyz,
                                                    const int* __restrict__ fps_idx, const int* __restrict__ knn,
                                                    double* __restrict__ partials){
  const int tid=threadIdx.x, wid=tid>>6, lane=tid&63;
  const int pid = blockIdx.x*4 + wid;
  const int b = pid>>11;
  const int fi = fps_idx[pid];
  const float* xb = x + (size_t)b*NPTS*CIN;
  const float* zb = xyz + (size_t)b*NPTS*3;
  const float lc0 = xb[fi*CIN + lane];
  float lc1 = 0.f; if (lane<32) lc1 = xb[fi*CIN + 64 + lane];
  float czv = 0.f; if (lane<3)  czv = zb[fi*3 + lane];
  double s1=0.0, s2=0.0, a1=0.0, a2=0.0;
  for (int k=0;k<NK;++k){
    int idx = knn[pid*NK + k];
    float d0 = __fsub_rn(xb[idx*CIN + lane], lc0);
    s1 += (double)d0; s2 += (double)d0*(double)d0;
    if (lane<32){
      float d1 = __fsub_rn(xb[idx*CIN + 64 + lane], lc1);
      s1 += (double)d1; s2 += (double)d1*(double)d1;
    }
    if (lane<3){
      float w = __fsub_rn(zb[idx*3 + lane], czv);
      a1 += (double)w; a2 += (double)w*(double)w;
    }
  }
#pragma unroll
  for (int off=32; off>0; off>>=1){ s1 += __shfl_xor(s1,off); s2 += __shfl_xor(s2,off); }
  __shared__ double shx[4][2];
  __shared__ double shz[4][3][2];
  if (lane==0){ shx[wid][0]=s1; shx[wid][1]=s2; }
  if (lane<3){ shz[wid][lane][0]=a1; shz[wid][lane][1]=a2; }
  __syncthreads();
  if (tid==0){
    double u0=0,u1=0;
    for (int w=0;w<4;++w){ u0+=shx[w][0]; u1+=shx[w][1]; }
    double* outp = partials + (size_t)blockIdx.x*8;
    outp[0]=u0; outp[1]=u1;
    for (int axq=0; axq<3; ++axq){
      double v0=0,v1=0;
      for (int w=0;w<4;++w){ v0+=shz[w][axq][0]; v1+=shz[w][axq][1]; }
      outp[2+2*axq]=v0; outp[3+2*axq]=v1;
    }
  }
}

__global__ void finalize_kernel(const double* __restrict__ partials, float* __restrict__ scal){
  const int lane = threadIdx.x;  // 64 threads, 1 wave
  double s1=0,s2=0;
  double z0a=0,z0b=0,z1a=0,z1b=0,z2a=0,z2b=0;
  for (int i=0;i<32;++i){
    const double* p = partials + (size_t)(lane*32+i)*8;   // 32 consecutive blocks -> same b
    s1+=p[0]; s2+=p[1];
    z0a+=p[2]; z0b+=p[3]; z1a+=p[4]; z1b+=p[5]; z2a+=p[6]; z2b+=p[7];
  }
#pragma unroll
  for (int off=32; off>0; off>>=1){ s1+=__shfl_xor(s1,off); s2+=__shfl_xor(s2,off); }
#pragma unroll
  for (int off=8; off>0; off>>=1){
    z0a+=__shfl_xor(z0a,off); z0b+=__shfl_xor(z0b,off);
    z1a+=__shfl_xor(z1a,off); z1b+=__shfl_xor(z1b,off);
    z2a+=__shfl_xor(z2a,off); z2b+=__shfl_xor(z2b,off);
  }
  __shared__ double zb[4][3][2];
  if ((lane&15)==0){
    int b = lane>>4;
    zb[b][0][0]=z0a; zb[b][0][1]=z0b;
    zb[b][1][0]=z1a; zb[b][1][1]=z1b;
    zb[b][2][0]=z2a; zb[b][2][1]=z2b;
  }
  __syncthreads();
  if (lane==0){
    double nx = (double)NB*NG*NK*CIN;
    double varx = (s2 - s1*s1/nx)/(nx-1.0);
    float stdx = (float)sqrt(varx);
    double t1=0,t2=0;
    for (int b=0;b<4;++b) for (int a=0;a<3;++a){ t1+=zb[b][a][0]; t2+=zb[b][a][1]; }
    double nz = (double)NB*NG*NK*3;
    double varz = (t2 - t1*t1/nz)/(nz-1.0);
    float stdz = (float)sqrt(varz);
    float sdiv = stdz + 1e-5f;
    double n2 = (double)NG*NK;
    double acc=0.0;
    for (int b=0;b<4;++b) for (int a=0;a<3;++a){
      double v = (zb[b][a][1] - zb[b][a][0]*zb[b][a][0]/n2)/(n2-1.0);
      acc += sqrt(v);
    }
    float gstd = (float)(acc/12.0) / sdiv;   // std(x4) = std(raw)/(std_xyz+1e-5)
    float sig = 0.26f*(1.0f+gstd) + 1e-6f;
    float blend = 1.0f/(1.0f + expf(-(gstd-0.1f)*10.0f));
    scal[0] = 1.0f/(stdx + 1e-5f);
    scal[1] = 1.0f/sdiv;
    scal[2] = 1.0f/sig;
    scal[3] = blend;
  }
}

// ---------------- main fused kernel: pe + weighting + max/mean over K -> lc in d_out ----------------
__global__ __launch_bounds__(256) void main_kernel(const float* __restrict__ x, const float* __restrict__ xyz,
                                                   const int* __restrict__ fps_idx, const int* __restrict__ knn,
                                                   const float* __restrict__ scal, float* __restrict__ lc_out){
  const int tid=threadIdx.x, wid=tid>>6, lane=tid&63;
  const int pid = blockIdx.x*4 + wid;
  const int b = pid>>11, g = pid&2047;
  const float inv_x = scal[0], inv_z = scal[1], inv_sig = scal[2], blend = scal[3];
  const float omb = 1.0f - blend;
  const int fi = fps_idx[pid];
  const float* xb = x + (size_t)b*NPTS*CIN;
  const float* zb = xyz + (size_t)b*NPTS*3;
  const float cx = zb[fi*3+0], cy = zb[fi*3+1], cz = zb[fi*3+2];
  // lane's 3 channels: c = lane, 64+lane, 128+lane
  const float lcx0 = xb[fi*CIN + lane];
  const float lcx1 = (lane<32) ? xb[fi*CIN + 64 + lane] : xb[fi*CIN + lane - 32];
  const float lcx2 = xb[fi*CIN + 32 + lane];
  // r0: fourier, dim = lane>>5 (0/1), rr = lane&31, freq = rr>>1, odd->cos
  const int dim0 = lane>>5;
  const int rr0 = lane&31;
  const bool cos0 = rr0 & 1;
  const float bs0 = 100.0f / powf(1000.0f, (float)(rr0>>1) * (1.0f/16.0f));
  // r1: lane<32 fourier dim=2; lane>=32 adaptive dim=0, j=lane-32
  const bool cos1 = lane & 1;
  const float bs1 = 100.0f / powf(1000.0f, (float)((lane&31)>>1) * (1.0f/16.0f));
  const float fv1 = (float)(-1.0 + 2.0*(double)(lane-32+1)/33.0);
  // r2: adaptive, cc=32+lane: dim=cc>>5 (1/2), j=cc&31
  const int dim2 = (32+lane)>>5;
  const int j2 = (32+lane)&31;
  const float fv2 = (float)(-1.0 + 2.0*(double)(j2+1)/33.0);

  float mx0=-INFINITY, mx1=-INFINITY, mx2=-INFINITY;
  float sm0=0.f, sm1=0.f, sm2=0.f;
  for (int k=0;k<NK;++k){
    const int idx = knn[pid*NK + k];
    const float p0 = zb[idx*3+0], p1 = zb[idx*3+1], p2v = zb[idx*3+2];
    const float xn0 = (p0-cx)*inv_z, xn1 = (p1-cy)*inv_z, xn2 = (p2v-cz)*inv_z;
    const float xk0 = xb[idx*CIN + lane];
    float xk1 = 0.f; if (lane<32) xk1 = xb[idx*CIN + 64 + lane];
    { // r0
      float v = dim0 ? xn1 : xn0;
      float a = v * bs0;
      float pe = cos0 ? __cosf(a) : __sinf(a);
      float f = (xk0 - lcx0) * inv_x;
      float w = (f + pe) * pe;
      mx0 = fmaxf(mx0, w); sm0 += w;
    }
    { // r1
      float pe, f;
      if (lane < 32){
        float a = xn2 * bs1;
        pe = cos1 ? __cosf(a) : __sinf(a);
        f = (xk1 - lcx1) * inv_x;
      } else {
        float zq = (xn0 - fv1) * inv_sig;
        pe = blend * __expf(-0.5f*zq*zq) + omb * __cosf(zq);
        f = lcx1;   // raw center features (second concat half)
      }
      float w = (f + pe) * pe;
      mx1 = fmaxf(mx1, w); sm1 += w;
    }
    { // r2
      float v = (dim2==1) ? xn1 : xn2;
      float zq = (v - fv2) * inv_sig;
      float pe = blend * __expf(-0.5f*zq*zq) + omb * __cosf(zq);
      float w = (lcx2 + pe) * pe;
      mx2 = fmaxf(mx2, w); sm2 += w;
    }
  }
  const size_t obase = ((size_t)b*COUT)*NG + g;
  lc_out[obase + (size_t)lane*NG]       = mx0 + sm0*(1.0f/32.0f);
  lc_out[obase + (size_t)(64+lane)*NG]  = mx1 + sm1*(1.0f/32.0f);
  lc_out[obase + (size_t)(128+lane)*NG] = mx2 + sm2*(1.0f/32.0f);
}

// ---------------- batch-norm stats (per channel over B,G; ddof=0) ----------------
__global__ __launch_bounds__(256) void bn_stats_kernel(const float* __restrict__ lc, float* __restrict__ bn){
  const int c = blockIdx.x, t = threadIdx.x, lane=t&63, wid=t>>6;
  double s1=0.0, s2=0.0;
  for (int i=t; i<NB*NG; i+=256){
    int b=i>>11, g=i&2047;
    float v = lc[((size_t)(b*COUT)+c)*NG + g];
    s1 += (double)v; s2 += (double)v*(double)v;
  }
#pragma unroll
  for (int off=32; off>0; off>>=1){ s1+=__shfl_xor(s1,off); s2+=__shfl_xor(s2,off); }
  __shared__ double sh1[4], sh2[4];
  if (lane==0){ sh1[wid]=s1; sh2[wid]=s2; }
  __syncthreads();
  if (t==0){
    double a=sh1[0]+sh1[1]+sh1[2]+sh1[3], q=sh2[0]+sh2[1]+sh2[2]+sh2[3];
    double n=(double)(NB*NG);
    double mu=a/n, var=q/n - mu*mu;
    bn[c]=(float)mu;
    bn[COUT+c]=(float)(1.0/sqrt(var + 1e-5));
  }
}

// ---------------- final: BN affine + exact gelu, in-place on d_out ----------------
__global__ __launch_bounds__(256) void final_kernel(const float* __restrict__ bn, const float* __restrict__ gamma,
                                                    const float* __restrict__ beta, float* __restrict__ out){
  int i = blockIdx.x*256 + threadIdx.x;
  int c = (i >> 11) % COUT;
  float v = out[i];
  float y = (v - bn[c]) * bn[COUT + c];
  y = y*gamma[c] + beta[c];
  out[i] = y * 0.5f * (1.0f + erff(y * 0.70710678118654752f));
}

extern "C" void kernel_launch(void* const* d_in, const int* in_sizes, int n_in,
                              void* d_out, int out_size, void* d_ws, size_t ws_size,
                              hipStream_t stream){
  const float* xyz   = (const float*)d_in[0];
  const float* x     = (const float*)d_in[1];
  const float* gamma = (const float*)d_in[2];
  const float* beta  = (const float*)d_in[3];
  float* out = (float*)d_out;
  char* ws = (char*)d_ws;
  // workspace layout (all regions fully written before read every launch)
  int*    fps  = (int*)   (ws + 0);        //  32 KB
  int*    knn  = (int*)   (ws + 32768);    //   1 MB
  float*  xs   = (float*) (ws + 1081344);  // 128 KB
  float*  ys   = (float*) (ws + 1212416);
  float*  zs   = (float*) (ws + 1343488);
  float*  d2   = (float*) (ws + 1474560);
  double* parts= (double*)(ws + 1605632);  // 2048*8 doubles
  float*  scal = (float*) (ws + 1736704);  // 4 floats
  float*  bn   = (float*) (ws + 1736768);  // 384 floats

  const int fps_lds = 131072 + 128 + 2048 + 192;   // ctab + keys[2][8] + hist + bbox scratch
  (void)hipFuncSetAttribute(reinterpret_cast<const void*>(fps_kernel),
                            hipFuncAttributeMaxDynamicSharedMemorySize, fps_lds);

  setup_kernel   <<<dim3((NB*NPTS+255)/256), dim3(256), 0, stream>>>(xyz, xs, ys, zs, d2);
  fps_kernel     <<<dim3(NB),                dim3(512), fps_lds, stream>>>(xyz, fps);
  knn_kernel     <<<dim3(NB*NG/4),           dim3(256), 0, stream>>>(xs, ys, zs, d2, fps, knn);
  stats_kernel   <<<dim3(NB*NG/4),           dim3(256), 0, stream>>>(x, xyz, fps, knn, parts);
  finalize_kernel<<<dim3(1),                 dim3(64),  0, stream>>>(parts, scal);
  main_kernel    <<<dim3(NB*NG/4),           dim3(256), 0, stream>>>(x, xyz, fps, knn, scal, out);
  bn_stats_kernel<<<dim3(COUT),              dim3(256), 0, stream>>>(out, bn);
  final_kernel   <<<dim3((NB*COUT*NG)/256),  dim3(256), 0, stream>>>(bn, gamma, beta, out);
}